// Round 7
// baseline (3135.469 us; speedup 1.0000x reference)
//
#include <hip/hip_runtime.h>

// ---------------------------------------------------------------------------
// VoxelSetAbstraction forward (PV-RCNN style) for MI355X
//   B=2, N_RAW=16384, N_KP=2048, M_VOX=8192, C_VOX=64
//   BEV: (2,256,200,176), stride 8, voxel 0.05, pc_min (0,-40,-3)
//   raw SA: radii (0.4,0.8) ns (16,16), MLP 4->16->16
//   conv SA: radii (1.2,2.4) ns (16,32), MLP 67->64->64
//   fusion: 416 -> 128
//
// r7: FUSED producer/consumer. fps (blocks 0,1; byte-identical r6 math)
// publishes keypoint progress every 16 via release/acquire agent atomics;
// 224 worker blocks consume keypoints incrementally and run bev+raw+conv+
// fusion per keypoint with the proven per-wave code. 86KB static LDS forces
// 1 block/CU and grid=226 <= 256 CUs => all blocks resident at launch =>
// no dispatch-order deadlock (G16-safe: only sync primitive is device-scope
// acquire/release on prog[], and the acquiring thread itself loads the
// coords it forwards).
// ---------------------------------------------------------------------------

#define NRAW    16384
#define MVOX    8192
#define NKP     2048
#define NKPALL  4096   // B * NKP
#define NWORKER 224
#define NBLK    (NWORKER + 2)

__device__ __constant__ float kBNS = (float)0.9999950000374997; // 1/sqrt(1+1e-5)

typedef float f32x2 __attribute__((ext_vector_type(2)));

// ---------------------------------------------------------------------------
// K0: pack points to interleaved float4 (x,y,z,intensity) + voxel centers
// ---------------------------------------------------------------------------
__global__ __launch_bounds__(256) void prep_kernel(
    const float* __restrict__ pts, const int* __restrict__ vc,
    float4* __restrict__ xyz4, float4* __restrict__ cxyz4) {
#pragma clang fp contract(off)
  int i = blockIdx.x * 256 + threadIdx.x;
  if (i < 2 * NRAW) {
    const float* p = pts + (size_t)i * 5;
    xyz4[i] = make_float4(p[1], p[2], p[3], p[4]);
  }
  if (i < 2 * MVOX) {
    const int* v = vc + (size_t)i * 4;
    cxyz4[i] = make_float4(((float)v[3] + 0.5f) * 0.2f + 0.0f,
                           ((float)v[2] + 0.5f) * 0.2f + -40.0f,
                           ((float)v[1] + 0.5f) * 0.4f + -3.0f, 0.f);
  }
}

// ---------------------------------------------------------------------------
// K0b: y-histogram sort (256 bins) per batch -> sperm (sorted-pos -> original
// local index). Proven-best y-slab binning (r0/r3/r4 A/B). FPS output is
// bin-order-invariant: ties resolved by ORIGINAL index carried in registers.
// ---------------------------------------------------------------------------
__global__ __launch_bounds__(1024) void sort_kernel(
    const float* __restrict__ pts, int* __restrict__ sperm) {
  const int b = blockIdx.x, t = threadIdx.x;
  __shared__ unsigned hist[256], cur[256];
  if (t < 256) hist[t] = 0u;
  __syncthreads();
  int bins[16];
#pragma unroll
  for (int k = 0; k < 16; ++k) {
    const int i = k * 1024 + t;
    const float y = pts[(size_t)(b * NRAW + i) * 5 + 2];
    int bin = (int)((y + 40.0f) * 3.2f);
    bin = bin < 0 ? 0 : (bin > 255 ? 255 : bin);
    bins[k] = bin;
    atomicAdd(&hist[bin], 1u);
  }
  __syncthreads();
  if (t == 0) {
    unsigned acc = 0;
    for (int i = 0; i < 256; ++i) { cur[i] = acc; acc += hist[i]; }
  }
  __syncthreads();
#pragma unroll
  for (int k = 0; k < 16; ++k) {
    const int i = k * 1024 + t;
    const unsigned pos = atomicAdd(&cur[bins[k]], 1u);
    sperm[b * NRAW + pos] = i;
  }
}

// Fused 64-bit DPP max-reduce stage (proven r6). After the 6-stage ladder the
// wave max of (hi:lo) lives in lane 63.
#define U64_STAGE(CTRL, RMASK)                                                 \
  {                                                                            \
    const unsigned tlo = (unsigned)__builtin_amdgcn_update_dpp(                \
        0, (int)lo, CTRL, RMASK, 0xf, true);                                   \
    const unsigned thi = (unsigned)__builtin_amdgcn_update_dpp(                \
        0, (int)hi, CTRL, RMASK, 0xf, true);                                   \
    const unsigned long long tv = ((unsigned long long)thi << 32) | tlo;       \
    const unsigned long long cv = ((unsigned long long)hi << 32) | lo;         \
    if (tv > cv) { hi = thi; lo = tlo; }                                       \
  }

// ---------------------------------------------------------------------------
// FUSED kernel: blocks 0,1 = fps (r6-identical math + periodic publish);
// blocks 2..225 = per-keypoint workers (bev + raw SA + conv SA + fusion).
// ---------------------------------------------------------------------------
__global__ __launch_bounds__(1024, 1) void fused_kernel(
    const int* __restrict__ sperm, const float4* __restrict__ xyz4,
    const float4* __restrict__ cxyz4, const float* __restrict__ vf,
    const float* __restrict__ sf,
    const float* __restrict__ rw0, const float* __restrict__ rg0,
    const float* __restrict__ rb0, const float* __restrict__ rw1,
    const float* __restrict__ rg1, const float* __restrict__ rb1,
    const float* __restrict__ cw0, const float* __restrict__ cg0,
    const float* __restrict__ cb0, const float* __restrict__ cw1,
    const float* __restrict__ cg1, const float* __restrict__ cb1,
    const float* __restrict__ fw, const float* __restrict__ fg,
    const float* __restrict__ fb,
    float* __restrict__ kx, float* __restrict__ ky, float* __restrict__ kz,
    int* prog, float* __restrict__ out) {
  const int t = threadIdx.x;
  const int wv = t >> 6, lane = t & 63;

  // ---- static LDS (86KB total -> forces 1 block/CU; grid 226 <= 256 CUs) ----
  __shared__ unsigned long long slot[3];                 // fps
  __shared__ float ldsW0[2 * 67 * 64];                   // conv w0 (34304B)
  __shared__ float ldsW1[2 * 64 * 64];                   // conv w1 (32768B)
  __shared__ int   idxlC[2][32];
  __shared__ __align__(16) float gbuf[2][64];
  __shared__ __align__(16) float hbufC[2][32][64];       // 16KB
  __shared__ int   idxlR[2][16];
  __shared__ float hbufR[2][16][17];
  __shared__ __align__(16) float featsL[416];
  __shared__ float kxyz[4];

  if (blockIdx.x < 2) {
    // =================== FPS (byte-identical r6 selection math) ===========
#pragma clang fp contract(off)
    const int b = blockIdx.x;
    const int wb = wv * 1024;
    const int base = b * NRAW;

    int pj[16];
    f32x2 px2[8], py2[8], pz2[8], dd2[8];
#pragma unroll
    for (int j = 0; j < 16; ++j)
      pj[j] = sperm[base + wb + j * 64 + lane];
#pragma unroll
    for (int j = 0; j < 16; ++j) {
      const float4 q = xyz4[base + pj[j]];  // gather; warms local L2
      px2[j >> 1][j & 1] = q.x;
      py2[j >> 1][j & 1] = q.y;
      pz2[j >> 1][j & 1] = q.z;
      dd2[j >> 1][j & 1] = 1e10f;
    }
    if (t < 3) slot[t] = 0ULL;

    float bnx = px2[0].x, bxx = px2[0].x, bny = py2[0].x, bxy = py2[0].x,
          bnz = pz2[0].x, bxz = pz2[0].x;
#pragma unroll
    for (int j = 1; j < 16; ++j) {
      bnx = fminf(bnx, px2[j >> 1][j & 1]); bxx = fmaxf(bxx, px2[j >> 1][j & 1]);
      bny = fminf(bny, py2[j >> 1][j & 1]); bxy = fmaxf(bxy, py2[j >> 1][j & 1]);
      bnz = fminf(bnz, pz2[j >> 1][j & 1]); bxz = fmaxf(bxz, pz2[j >> 1][j & 1]);
    }
#pragma unroll
    for (int off = 1; off < 64; off <<= 1) {
      bnx = fminf(bnx, __shfl_xor(bnx, off, 64));
      bxx = fmaxf(bxx, __shfl_xor(bxx, off, 64));
      bny = fminf(bny, __shfl_xor(bny, off, 64));
      bxy = fmaxf(bxy, __shfl_xor(bxy, off, 64));
      bnz = fminf(bnz, __shfl_xor(bnz, off, 64));
      bxz = fmaxf(bxz, __shfl_xor(bxz, off, 64));
    }

    const float4 p0 = xyz4[base];
    float lx = p0.x, ly = p0.y, lz = p0.z;
    if (t == 0) { kx[b * NKP] = lx; ky[b * NKP] = ly; kz[b * NKP] = lz; }

    unsigned long long cpk = 0ULL;
    float bvc = __builtin_inff();
    __syncthreads();

    for (int s = 1; s < NKP; ++s) {
      float dxm = fmaxf(fmaxf(bnx - lx, lx - bxx), 0.f);
      float dym = fmaxf(fmaxf(bny - ly, ly - bxy), 0.f);
      float dzm = fmaxf(fmaxf(bnz - lz, lz - bxz), 0.f);
      const float LB2 = dxm * dxm + dym * dym + dzm * dzm;
      if (!(LB2 * 0.9999f > bvc)) {       // active
        const f32x2 lx2 = {lx, lx}, ly2 = {ly, ly}, lz2 = {lz, lz};
#pragma unroll
        for (int j8 = 0; j8 < 8; ++j8) {
          f32x2 dx = px2[j8] - lx2;
          f32x2 dy = py2[j8] - ly2;
          f32x2 dz = pz2[j8] - lz2;
          f32x2 d2 = dx * dx;
          d2 = d2 + dy * dy;
          d2 = d2 + dz * dz;
          dd2[j8] = __builtin_elementwise_min(dd2[j8], d2);
        }
        f32x2 t0 = __builtin_elementwise_max(dd2[0], dd2[1]);
        f32x2 t1 = __builtin_elementwise_max(dd2[2], dd2[3]);
        f32x2 t2 = __builtin_elementwise_max(dd2[4], dd2[5]);
        f32x2 t3 = __builtin_elementwise_max(dd2[6], dd2[7]);
        t0 = __builtin_elementwise_max(t0, t1);
        t2 = __builtin_elementwise_max(t2, t3);
        t0 = __builtin_elementwise_max(t0, t2);
        const float bv = fmaxf(t0.x, t0.y);
        const unsigned vb = __float_as_uint(bv);
        unsigned mo = 0xFFFFFFFFu;
#pragma unroll
        for (int j = 0; j < 16; ++j)
          if (__float_as_uint(dd2[j >> 1][j & 1]) == vb) {
            const unsigned o = (unsigned)pj[j];
            mo = o < mo ? o : mo;
          }
        unsigned hi = vb, lo = ~mo;
        U64_STAGE(0xB1,  0xf)
        U64_STAGE(0x4E,  0xf)
        U64_STAGE(0x124, 0xf)
        U64_STAGE(0x128, 0xf)
        U64_STAGE(0x142, 0xa)
        U64_STAGE(0x143, 0xc)
        bvc = __uint_as_float(
            (unsigned)__builtin_amdgcn_readlane((int)hi, 63));
        cpk = ((unsigned long long)hi << 32) | (unsigned long long)lo;
      }
      if (lane == 63) atomicMax(&slot[s % 3], cpk);
      __syncthreads();

      const unsigned long long g = slot[s % 3];
      const int wi = __builtin_amdgcn_readfirstlane((int)~(unsigned)g);
      if (t == 0) slot[(s + 2) % 3] = 0ULL;
      const float4 cw = xyz4[base + wi];
      lx = cw.x; ly = cw.y; lz = cw.z;
      if (t == 0) {
        kx[b * NKP + s] = lx; ky[b * NKP + s] = ly; kz[b * NKP + s] = lz;
        if ((s & 15) == 15)   // publish 16 keypoints (release orders kx/ky/kz)
          __hip_atomic_store(&prog[b], s + 1, __ATOMIC_RELEASE,
                             __HIP_MEMORY_SCOPE_AGENT);
      }
    }
  } else {
    // =================== WORKER: one keypoint per pass =====================
    // stage conv weights to LDS once (values identical to global)
    for (int i = t; i < 2 * 67 * 64; i += 1024) ldsW0[i] = cw0[i];
    for (int i = t; i < 2 * 64 * 64; i += 1024) ldsW1[i] = cw1[i];
    __syncthreads();

    const int wkr = (int)blockIdx.x - 2;
    for (int g = wkr; g < NKPALL; g += NWORKER) {
      const int bb = g >> 11, s = g & 2047;
      const int kidx = g;
      if (t == 0) {
        while (__hip_atomic_load(&prog[bb], __ATOMIC_ACQUIRE,
                                 __HIP_MEMORY_SCOPE_AGENT) <= s)
          __builtin_amdgcn_s_sleep(8);
        kxyz[0] = kx[kidx]; kxyz[1] = ky[kidx]; kxyz[2] = kz[kidx];
      }
      __syncthreads();
      const float kxv = kxyz[0], kyv = kxyz[1], kzv = kxyz[2];

      if (wv < 2) {
        // ---- raw SA (identical math to raw_sa_kernel), ri = wv ----
        const int ri = wv;
        const float R2 = ri ? (float)(0.8 * 0.8) : (float)(0.4 * 0.4);
        const int rbase = bb * NRAW;
        int cnt = 0;
        {
#pragma clang fp contract(off)
          for (int ch = 0; ch < NRAW / 64 && cnt < 16; ++ch) {
            const float4 q = xyz4[rbase + ch * 64 + lane];
            float dx = kxv - q.x, dy = kyv - q.y, dz = kzv - q.z;
            float d2 = dx * dx; d2 = d2 + dy * dy; d2 = d2 + dz * dz;
            unsigned long long m = __ballot(d2 < R2);
            while (m && cnt < 16) {
              int bit = __builtin_ctzll(m);
              if (lane == 0) idxlR[ri][cnt] = ch * 64 + bit;
              ++cnt;
              m &= m - 1;
            }
          }
        }
        const int outoff = 256 + ri * 16;
        if (cnt == 0) {
          if (lane < 16) featsL[outoff + lane] = 0.f;
        } else {
          __threadfence_block();
          const int sL = lane & 15, cq = lane >> 4;
          const int ss = (sL < cnt) ? sL : 0;
          const float4 q = xyz4[rbase + idxlR[ri][ss]];
          const float gx = q.x - kxv, gy = q.y - kyv, gz = q.z - kzv, gi = q.w;
          const int wb0 = ri * 64, cb = ri * 16;
#pragma unroll
          for (int j = 0; j < 4; ++j) {
            int c = cq * 4 + j;
            float a = gx * rw0[wb0 + c];
            a = fmaf(gy, rw0[wb0 + 16 + c], a);
            a = fmaf(gz, rw0[wb0 + 32 + c], a);
            a = fmaf(gi, rw0[wb0 + 48 + c], a);
            a = fmaf(a, rg0[cb + c] * kBNS, rb0[cb + c]);
            hbufR[ri][sL][c] = fmaxf(a, 0.f);
          }
          __threadfence_block();
          float o0 = 0.f, o1 = 0.f, o2 = 0.f, o3 = 0.f;
          const int wb1 = ri * 256;
#pragma unroll
          for (int k = 0; k < 16; ++k) {
            float hk = hbufR[ri][sL][k];
            o0 = fmaf(hk, rw1[wb1 + k * 16 + cq * 4 + 0], o0);
            o1 = fmaf(hk, rw1[wb1 + k * 16 + cq * 4 + 1], o1);
            o2 = fmaf(hk, rw1[wb1 + k * 16 + cq * 4 + 2], o2);
            o3 = fmaf(hk, rw1[wb1 + k * 16 + cq * 4 + 3], o3);
          }
          float v0 = fmaxf(fmaf(o0, rg1[cb + cq * 4 + 0] * kBNS, rb1[cb + cq * 4 + 0]), 0.f);
          float v1 = fmaxf(fmaf(o1, rg1[cb + cq * 4 + 1] * kBNS, rb1[cb + cq * 4 + 1]), 0.f);
          float v2 = fmaxf(fmaf(o2, rg1[cb + cq * 4 + 2] * kBNS, rb1[cb + cq * 4 + 2]), 0.f);
          float v3 = fmaxf(fmaf(o3, rg1[cb + cq * 4 + 3] * kBNS, rb1[cb + cq * 4 + 3]), 0.f);
#pragma unroll
          for (int off = 1; off < 16; off <<= 1) {
            v0 = fmaxf(v0, __shfl_xor(v0, off, 64));
            v1 = fmaxf(v1, __shfl_xor(v1, off, 64));
            v2 = fmaxf(v2, __shfl_xor(v2, off, 64));
            v3 = fmaxf(v3, __shfl_xor(v3, off, 64));
          }
          if (sL == 0) {
            featsL[outoff + cq * 4 + 0] = v0;
            featsL[outoff + cq * 4 + 1] = v1;
            featsL[outoff + cq * 4 + 2] = v2;
            featsL[outoff + cq * 4 + 3] = v3;
          }
        }
      } else if (wv < 4) {
        // ---- conv SA (identical math; weights from LDS), ri = wv-2 ----
        const int ri = wv - 2;
        const int NS = ri ? 32 : 16;
        const float R2 = ri ? (float)(2.4 * 2.4) : (float)(1.2 * 1.2);
        const int cbase = bb * MVOX;
        int cnt = 0;
        {
#pragma clang fp contract(off)
          for (int ch = 0; ch < MVOX / 64 && cnt < NS; ++ch) {
            const float4 q = cxyz4[cbase + ch * 64 + lane];
            float dx = kxv - q.x, dy = kyv - q.y, dz = kzv - q.z;
            float d2 = dx * dx; d2 = d2 + dy * dy; d2 = d2 + dz * dz;
            unsigned long long m = __ballot(d2 < R2);
            while (m && cnt < NS) {
              int bit = __builtin_ctzll(m);
              if (lane == 0) idxlC[ri][cnt] = ch * 64 + bit;
              ++cnt;
              m &= m - 1;
            }
          }
        }
        const int outoff = 288 + ri * 64;
        if (cnt == 0) {
          featsL[outoff + lane] = 0.f;
        } else {
          __threadfence_block();
          const float wA0 = ldsW0[(ri * 67 + 0) * 64 + lane];
          const float wA1 = ldsW0[(ri * 67 + 1) * 64 + lane];
          const float wA2 = ldsW0[(ri * 67 + 2) * 64 + lane];
          const float* wB = &ldsW0[(ri * 67 + 3) * 64 + lane];
          const float* wC = &ldsW1[ri * 64 * 64 + lane];
          const float s0 = cg0[ri * 64 + lane] * kBNS, bb0 = cb0[ri * 64 + lane];
          const float s1 = cg1[ri * 64 + lane] * kBNS, bb1 = cb1[ri * 64 + lane];
          for (int sm = 0; sm < cnt; ++sm) {
            const int p = cbase + idxlC[ri][sm];
            const float4 q = cxyz4[p];
            const float ox = q.x - kxv, oy = q.y - kyv, oz = q.z - kzv;
            gbuf[ri][lane] = vf[(size_t)p * 64 + lane];
            __threadfence_block();
            float acc = ox * wA0;
            acc = fmaf(oy, wA1, acc);
            acc = fmaf(oz, wA2, acc);
#pragma unroll
            for (int k4 = 0; k4 < 16; ++k4) {
              float4 g4 = *(const float4*)&gbuf[ri][k4 * 4];
              acc = fmaf(g4.x, wB[(k4 * 4 + 0) * 64], acc);
              acc = fmaf(g4.y, wB[(k4 * 4 + 1) * 64], acc);
              acc = fmaf(g4.z, wB[(k4 * 4 + 2) * 64], acc);
              acc = fmaf(g4.w, wB[(k4 * 4 + 3) * 64], acc);
            }
            hbufC[ri][sm][lane] = fmaxf(fmaf(acc, s0, bb0), 0.f);
            __threadfence_block();
          }
          float mx = -1e30f;
          for (int sm = 0; sm < cnt; ++sm) {
            float acc = 0.f;
#pragma unroll
            for (int k4 = 0; k4 < 16; ++k4) {
              float4 h4 = *(const float4*)&hbufC[ri][sm][k4 * 4];
              acc = fmaf(h4.x, wC[(k4 * 4 + 0) * 64], acc);
              acc = fmaf(h4.y, wC[(k4 * 4 + 1) * 64], acc);
              acc = fmaf(h4.z, wC[(k4 * 4 + 2) * 64], acc);
              acc = fmaf(h4.w, wC[(k4 * 4 + 3) * 64], acc);
            }
            mx = fmaxf(mx, fmaxf(fmaf(acc, s1, bb1), 0.f));
          }
          featsL[outoff + lane] = mx;
        }
      } else if (wv < 8) {
        // ---- BEV bilinear (identical math), c = t-256 ----
#pragma clang fp contract(off)
        const int c = t - 256;
        const float x = (kxv - 0.0f) / 0.05f / 8.0f;
        const float y = (kyv - (-40.0f)) / 0.05f / 8.0f;
        const float xf = floorf(x), yf = floorf(y);
        int x0 = (int)xf;     x0 = x0 < 0 ? 0 : (x0 > 175 ? 175 : x0);
        int x1 = (int)xf + 1; x1 = x1 < 0 ? 0 : (x1 > 175 ? 175 : x1);
        int y0 = (int)yf;     y0 = y0 < 0 ? 0 : (y0 > 199 ? 199 : y0);
        int y1 = (int)yf + 1; y1 = y1 < 0 ? 0 : (y1 > 199 ? 199 : y1);
        const float x0f = (float)x0, x1f = (float)x1, y0f = (float)y0, y1f = (float)y1;
        const float wa = (x - x0f) * (y1f - y);
        const float wbv = (x1f - x) * (y1f - y);
        const float wc = (x1f - x) * (y - y0f);
        const float wd = (x - x0f) * (y - y0f);
        const float* bsf = sf + ((size_t)bb * 256 + c) * (200 * 176);
        const float fa = bsf[y1 * 176 + x0];
        const float fbv = bsf[y1 * 176 + x1];
        const float fc = bsf[y0 * 176 + x1];
        const float fd = bsf[y0 * 176 + x0];
        float r = fd * wbv; r = r + fc * wa; r = r + fa * wc; r = r + fbv * wd;
        featsL[c] = r;
      }
      __syncthreads();

      // ---- fusion 416 -> 128 (identical math), c = t ----
      if (t < 128) {
        const int c = t;
        float acc = 0.f;
#pragma unroll 4
        for (int k = 0; k < 416; k += 4) {
          float4 fv = *(const float4*)(featsL + k);
          acc = fmaf(fv.x, fw[(k + 0) * 128 + c], acc);
          acc = fmaf(fv.y, fw[(k + 1) * 128 + c], acc);
          acc = fmaf(fv.z, fw[(k + 2) * 128 + c], acc);
          acc = fmaf(fv.w, fw[(k + 3) * 128 + c], acc);
        }
        out[(size_t)kidx * 128 + c] =
            fmaxf(fmaf(acc, fg[c] * kBNS, fb[c]), 0.f);
      }
      __syncthreads();   // featsL reused next keypoint
    }
  }
}

// ---------------------------------------------------------------------------
extern "C" void kernel_launch(void* const* d_in, const int* in_sizes, int n_in,
                              void* d_out, int out_size, void* d_ws, size_t ws_size,
                              hipStream_t stream) {
  (void)in_sizes; (void)n_in; (void)out_size; (void)ws_size;
  const float* pts = (const float*)d_in[0];
  const float* sf  = (const float*)d_in[1];
  const int*   vc  = (const int*)d_in[2];
  const float* vf  = (const float*)d_in[3];
  const float* raw_w0 = (const float*)d_in[4];
  const float* raw_g0 = (const float*)d_in[5];
  const float* raw_b0 = (const float*)d_in[6];
  const float* raw_w1 = (const float*)d_in[7];
  const float* raw_g1 = (const float*)d_in[8];
  const float* raw_b1 = (const float*)d_in[9];
  const float* conv_w0 = (const float*)d_in[10];
  const float* conv_g0 = (const float*)d_in[11];
  const float* conv_b0 = (const float*)d_in[12];
  const float* conv_w1 = (const float*)d_in[13];
  const float* conv_g1 = (const float*)d_in[14];
  const float* conv_b1 = (const float*)d_in[15];
  const float* fus_w = (const float*)d_in[16];
  const float* fus_g = (const float*)d_in[17];
  const float* fus_b = (const float*)d_in[18];
  float* out = (float*)d_out;

  float* W = (float*)d_ws;
  float4* xyz4  = (float4*)W;             // 32768 float4 = 131072 floats
  float4* cxyz4 = (float4*)(W + 131072);  // 16384 float4 = 65536 floats
  float* kx    = W + 196608;              // 4096 each
  float* ky    = W + 200704;
  float* kz    = W + 204800;
  int*   prog  = (int*)(W + 208896);      // 2 ints, zeroed per launch
  int*   sperm = (int*)(W + 209920);      // 32768 ints

  hipMemsetAsync(prog, 0, 2 * sizeof(int), stream);
  prep_kernel<<<128, 256, 0, stream>>>(pts, vc, xyz4, cxyz4);
  sort_kernel<<<2, 1024, 0, stream>>>(pts, sperm);
  fused_kernel<<<NBLK, 1024, 0, stream>>>(
      sperm, xyz4, cxyz4, vf, sf,
      raw_w0, raw_g0, raw_b0, raw_w1, raw_g1, raw_b1,
      conv_w0, conv_g0, conv_b0, conv_w1, conv_g1, conv_b1,
      fus_w, fus_g, fus_b, kx, ky, kz, prog, out);
}

// Round 8
// 3027.683 us; speedup vs baseline: 1.0356x; 1.0356x over previous
//
#include <hip/hip_runtime.h>

// ---------------------------------------------------------------------------
// VoxelSetAbstraction forward (PV-RCNN style) for MI355X
//   B=2, N_RAW=16384, N_KP=2048, M_VOX=8192, C_VOX=64
//   BEV: (2,256,200,176), stride 8, voxel 0.05, pc_min (0,-40,-3)
//   raw SA: radii (0.4,0.8) ns (16,16), MLP 4->16->16
//   conv SA: radii (1.2,2.4) ns (16,32), MLP 67->64->64
//   fusion: 416 -> 128
//
// r8: r7 fused producer/consumer with QUIET consumers.
//   r7 evidence: 444MB HBM traffic ~= 224 pollers * 200ns agent-acquire spin
//   -> coherence storm slowed fps 1694->3000us. Fixes:
//   (1) poll period 200ns -> ~13.6us (4x s_sleep(127)): probe traffic ~70x
//       down; worker slack/kp ~80us >> overshoot, only final tail pays ~15us.
//   (2) workers on fps's (heuristic) XCDs exit: blockIdx&7 in {0,1} -> 168
//       workers remain (still ~8x production rate); fps XCD-local L2 serves
//       only fps (protects the winner s_load on the serial chain).
// Math byte-identical to r7 (which passed verification).
// ---------------------------------------------------------------------------

#define NRAW    16384
#define MVOX    8192
#define NKP     2048
#define NKPALL  4096   // B * NKP
#define NWORKER 168    // included workers after XCD exclusion
#define NBLK    226    // 2 fps + 224 worker slots (56 exit immediately)

__device__ __constant__ float kBNS = (float)0.9999950000374997; // 1/sqrt(1+1e-5)

typedef float f32x2 __attribute__((ext_vector_type(2)));

// ---------------------------------------------------------------------------
// K0: pack points to interleaved float4 (x,y,z,intensity) + voxel centers
// ---------------------------------------------------------------------------
__global__ __launch_bounds__(256) void prep_kernel(
    const float* __restrict__ pts, const int* __restrict__ vc,
    float4* __restrict__ xyz4, float4* __restrict__ cxyz4) {
#pragma clang fp contract(off)
  int i = blockIdx.x * 256 + threadIdx.x;
  if (i < 2 * NRAW) {
    const float* p = pts + (size_t)i * 5;
    xyz4[i] = make_float4(p[1], p[2], p[3], p[4]);
  }
  if (i < 2 * MVOX) {
    const int* v = vc + (size_t)i * 4;
    cxyz4[i] = make_float4(((float)v[3] + 0.5f) * 0.2f + 0.0f,
                           ((float)v[2] + 0.5f) * 0.2f + -40.0f,
                           ((float)v[1] + 0.5f) * 0.4f + -3.0f, 0.f);
  }
}

// ---------------------------------------------------------------------------
// K0b: y-histogram sort (256 bins) per batch -> sperm (sorted-pos -> original
// local index). Proven-best y-slab binning (r0/r3/r4 A/B). FPS output is
// bin-order-invariant: ties resolved by ORIGINAL index carried in registers.
// ---------------------------------------------------------------------------
__global__ __launch_bounds__(1024) void sort_kernel(
    const float* __restrict__ pts, int* __restrict__ sperm) {
  const int b = blockIdx.x, t = threadIdx.x;
  __shared__ unsigned hist[256], cur[256];
  if (t < 256) hist[t] = 0u;
  __syncthreads();
  int bins[16];
#pragma unroll
  for (int k = 0; k < 16; ++k) {
    const int i = k * 1024 + t;
    const float y = pts[(size_t)(b * NRAW + i) * 5 + 2];
    int bin = (int)((y + 40.0f) * 3.2f);
    bin = bin < 0 ? 0 : (bin > 255 ? 255 : bin);
    bins[k] = bin;
    atomicAdd(&hist[bin], 1u);
  }
  __syncthreads();
  if (t == 0) {
    unsigned acc = 0;
    for (int i = 0; i < 256; ++i) { cur[i] = acc; acc += hist[i]; }
  }
  __syncthreads();
#pragma unroll
  for (int k = 0; k < 16; ++k) {
    const int i = k * 1024 + t;
    const unsigned pos = atomicAdd(&cur[bins[k]], 1u);
    sperm[b * NRAW + pos] = i;
  }
}

// Fused 64-bit DPP max-reduce stage (proven r6). After the 6-stage ladder the
// wave max of (hi:lo) lives in lane 63.
#define U64_STAGE(CTRL, RMASK)                                                 \
  {                                                                            \
    const unsigned tlo = (unsigned)__builtin_amdgcn_update_dpp(                \
        0, (int)lo, CTRL, RMASK, 0xf, true);                                   \
    const unsigned thi = (unsigned)__builtin_amdgcn_update_dpp(                \
        0, (int)hi, CTRL, RMASK, 0xf, true);                                   \
    const unsigned long long tv = ((unsigned long long)thi << 32) | tlo;       \
    const unsigned long long cv = ((unsigned long long)hi << 32) | lo;         \
    if (tv > cv) { hi = thi; lo = tlo; }                                       \
  }

// ---------------------------------------------------------------------------
// FUSED kernel: blocks 0,1 = fps (r6-identical math + periodic publish);
// included workers = per-keypoint consumers (bev + raw SA + conv SA + fusion).
// ---------------------------------------------------------------------------
__global__ __launch_bounds__(1024, 1) void fused_kernel(
    const int* __restrict__ sperm, const float4* __restrict__ xyz4,
    const float4* __restrict__ cxyz4, const float* __restrict__ vf,
    const float* __restrict__ sf,
    const float* __restrict__ rw0, const float* __restrict__ rg0,
    const float* __restrict__ rb0, const float* __restrict__ rw1,
    const float* __restrict__ rg1, const float* __restrict__ rb1,
    const float* __restrict__ cw0, const float* __restrict__ cg0,
    const float* __restrict__ cb0, const float* __restrict__ cw1,
    const float* __restrict__ cg1, const float* __restrict__ cb1,
    const float* __restrict__ fw, const float* __restrict__ fg,
    const float* __restrict__ fb,
    float* __restrict__ kx, float* __restrict__ ky, float* __restrict__ kz,
    int* prog, float* __restrict__ out) {
  const int t = threadIdx.x;
  const int wv = t >> 6, lane = t & 63;

  // ---- static LDS (86KB total -> forces 1 block/CU; grid 226 <= 256 CUs) ----
  __shared__ unsigned long long slot[3];                 // fps
  __shared__ float ldsW0[2 * 67 * 64];                   // conv w0 (34304B)
  __shared__ float ldsW1[2 * 64 * 64];                   // conv w1 (32768B)
  __shared__ int   idxlC[2][32];
  __shared__ __align__(16) float gbuf[2][64];
  __shared__ __align__(16) float hbufC[2][32][64];       // 16KB
  __shared__ int   idxlR[2][16];
  __shared__ float hbufR[2][16][17];
  __shared__ __align__(16) float featsL[416];
  __shared__ float kxyz[4];

  if (blockIdx.x < 2) {
    // =================== FPS (byte-identical r6 selection math) ===========
#pragma clang fp contract(off)
    const int b = blockIdx.x;
    const int wb = wv * 1024;
    const int base = b * NRAW;

    int pj[16];
    f32x2 px2[8], py2[8], pz2[8], dd2[8];
#pragma unroll
    for (int j = 0; j < 16; ++j)
      pj[j] = sperm[base + wb + j * 64 + lane];
#pragma unroll
    for (int j = 0; j < 16; ++j) {
      const float4 q = xyz4[base + pj[j]];  // gather; warms local L2
      px2[j >> 1][j & 1] = q.x;
      py2[j >> 1][j & 1] = q.y;
      pz2[j >> 1][j & 1] = q.z;
      dd2[j >> 1][j & 1] = 1e10f;
    }
    if (t < 3) slot[t] = 0ULL;

    float bnx = px2[0].x, bxx = px2[0].x, bny = py2[0].x, bxy = py2[0].x,
          bnz = pz2[0].x, bxz = pz2[0].x;
#pragma unroll
    for (int j = 1; j < 16; ++j) {
      bnx = fminf(bnx, px2[j >> 1][j & 1]); bxx = fmaxf(bxx, px2[j >> 1][j & 1]);
      bny = fminf(bny, py2[j >> 1][j & 1]); bxy = fmaxf(bxy, py2[j >> 1][j & 1]);
      bnz = fminf(bnz, pz2[j >> 1][j & 1]); bxz = fmaxf(bxz, pz2[j >> 1][j & 1]);
    }
#pragma unroll
    for (int off = 1; off < 64; off <<= 1) {
      bnx = fminf(bnx, __shfl_xor(bnx, off, 64));
      bxx = fmaxf(bxx, __shfl_xor(bxx, off, 64));
      bny = fminf(bny, __shfl_xor(bny, off, 64));
      bxy = fmaxf(bxy, __shfl_xor(bxy, off, 64));
      bnz = fminf(bnz, __shfl_xor(bnz, off, 64));
      bxz = fmaxf(bxz, __shfl_xor(bxz, off, 64));
    }

    const float4 p0 = xyz4[base];
    float lx = p0.x, ly = p0.y, lz = p0.z;
    if (t == 0) { kx[b * NKP] = lx; ky[b * NKP] = ly; kz[b * NKP] = lz; }

    unsigned long long cpk = 0ULL;
    float bvc = __builtin_inff();
    __syncthreads();

    for (int s = 1; s < NKP; ++s) {
      float dxm = fmaxf(fmaxf(bnx - lx, lx - bxx), 0.f);
      float dym = fmaxf(fmaxf(bny - ly, ly - bxy), 0.f);
      float dzm = fmaxf(fmaxf(bnz - lz, lz - bxz), 0.f);
      const float LB2 = dxm * dxm + dym * dym + dzm * dzm;
      if (!(LB2 * 0.9999f > bvc)) {       // active
        const f32x2 lx2 = {lx, lx}, ly2 = {ly, ly}, lz2 = {lz, lz};
#pragma unroll
        for (int j8 = 0; j8 < 8; ++j8) {
          f32x2 dx = px2[j8] - lx2;
          f32x2 dy = py2[j8] - ly2;
          f32x2 dz = pz2[j8] - lz2;
          f32x2 d2 = dx * dx;
          d2 = d2 + dy * dy;
          d2 = d2 + dz * dz;
          dd2[j8] = __builtin_elementwise_min(dd2[j8], d2);
        }
        f32x2 t0 = __builtin_elementwise_max(dd2[0], dd2[1]);
        f32x2 t1 = __builtin_elementwise_max(dd2[2], dd2[3]);
        f32x2 t2 = __builtin_elementwise_max(dd2[4], dd2[5]);
        f32x2 t3 = __builtin_elementwise_max(dd2[6], dd2[7]);
        t0 = __builtin_elementwise_max(t0, t1);
        t2 = __builtin_elementwise_max(t2, t3);
        t0 = __builtin_elementwise_max(t0, t2);
        const float bv = fmaxf(t0.x, t0.y);
        const unsigned vb = __float_as_uint(bv);
        unsigned mo = 0xFFFFFFFFu;
#pragma unroll
        for (int j = 0; j < 16; ++j)
          if (__float_as_uint(dd2[j >> 1][j & 1]) == vb) {
            const unsigned o = (unsigned)pj[j];
            mo = o < mo ? o : mo;
          }
        unsigned hi = vb, lo = ~mo;
        U64_STAGE(0xB1,  0xf)
        U64_STAGE(0x4E,  0xf)
        U64_STAGE(0x124, 0xf)
        U64_STAGE(0x128, 0xf)
        U64_STAGE(0x142, 0xa)
        U64_STAGE(0x143, 0xc)
        bvc = __uint_as_float(
            (unsigned)__builtin_amdgcn_readlane((int)hi, 63));
        cpk = ((unsigned long long)hi << 32) | (unsigned long long)lo;
      }
      if (lane == 63) atomicMax(&slot[s % 3], cpk);
      __syncthreads();

      const unsigned long long g = slot[s % 3];
      const int wi = __builtin_amdgcn_readfirstlane((int)~(unsigned)g);
      if (t == 0) slot[(s + 2) % 3] = 0ULL;
      const float4 cw = xyz4[base + wi];
      lx = cw.x; ly = cw.y; lz = cw.z;
      if (t == 0) {
        kx[b * NKP + s] = lx; ky[b * NKP + s] = ly; kz[b * NKP + s] = lz;
        if ((s & 15) == 15)   // publish 16 keypoints (release orders kx/ky/kz)
          __hip_atomic_store(&prog[b], s + 1, __ATOMIC_RELEASE,
                             __HIP_MEMORY_SCOPE_AGENT);
      }
    }
  } else {
    // =================== WORKER: one keypoint per pass =====================
    const int bi = (int)blockIdx.x;
    const int sub = bi & 7;
    if (sub < 2) return;   // heuristic: keep fps blocks' XCD-local L2 clean
    const int wkr = (bi >> 3) * 6 + (sub - 2);   // 0..167

    // stage conv weights to LDS once (values identical to global)
    for (int i = t; i < 2 * 67 * 64; i += 1024) ldsW0[i] = cw0[i];
    for (int i = t; i < 2 * 64 * 64; i += 1024) ldsW1[i] = cw1[i];
    __syncthreads();

    for (int g = wkr; g < NKPALL; g += NWORKER) {
      const int bb = g >> 11, s = g & 2047;
      const int kidx = g;
      if (t == 0) {
        // quiet wait: ~13.6us probe period (4x s_sleep(127)); acquire on the
        // probe orders the subsequent kx/ky/kz reads.
        while (__hip_atomic_load(&prog[bb], __ATOMIC_ACQUIRE,
                                 __HIP_MEMORY_SCOPE_AGENT) <= s) {
          __builtin_amdgcn_s_sleep(127);
          __builtin_amdgcn_s_sleep(127);
          __builtin_amdgcn_s_sleep(127);
          __builtin_amdgcn_s_sleep(127);
        }
        kxyz[0] = kx[kidx]; kxyz[1] = ky[kidx]; kxyz[2] = kz[kidx];
      }
      __syncthreads();
      const float kxv = kxyz[0], kyv = kxyz[1], kzv = kxyz[2];

      if (wv < 2) {
        // ---- raw SA (identical math to raw_sa_kernel), ri = wv ----
        const int ri = wv;
        const float R2 = ri ? (float)(0.8 * 0.8) : (float)(0.4 * 0.4);
        const int rbase = bb * NRAW;
        int cnt = 0;
        {
#pragma clang fp contract(off)
          for (int ch = 0; ch < NRAW / 64 && cnt < 16; ++ch) {
            const float4 q = xyz4[rbase + ch * 64 + lane];
            float dx = kxv - q.x, dy = kyv - q.y, dz = kzv - q.z;
            float d2 = dx * dx; d2 = d2 + dy * dy; d2 = d2 + dz * dz;
            unsigned long long m = __ballot(d2 < R2);
            while (m && cnt < 16) {
              int bit = __builtin_ctzll(m);
              if (lane == 0) idxlR[ri][cnt] = ch * 64 + bit;
              ++cnt;
              m &= m - 1;
            }
          }
        }
        const int outoff = 256 + ri * 16;
        if (cnt == 0) {
          if (lane < 16) featsL[outoff + lane] = 0.f;
        } else {
          __threadfence_block();
          const int sL = lane & 15, cq = lane >> 4;
          const int ss = (sL < cnt) ? sL : 0;
          const float4 q = xyz4[rbase + idxlR[ri][ss]];
          const float gx = q.x - kxv, gy = q.y - kyv, gz = q.z - kzv, gi = q.w;
          const int wb0 = ri * 64, cb = ri * 16;
#pragma unroll
          for (int j = 0; j < 4; ++j) {
            int c = cq * 4 + j;
            float a = gx * rw0[wb0 + c];
            a = fmaf(gy, rw0[wb0 + 16 + c], a);
            a = fmaf(gz, rw0[wb0 + 32 + c], a);
            a = fmaf(gi, rw0[wb0 + 48 + c], a);
            a = fmaf(a, rg0[cb + c] * kBNS, rb0[cb + c]);
            hbufR[ri][sL][c] = fmaxf(a, 0.f);
          }
          __threadfence_block();
          float o0 = 0.f, o1 = 0.f, o2 = 0.f, o3 = 0.f;
          const int wb1 = ri * 256;
#pragma unroll
          for (int k = 0; k < 16; ++k) {
            float hk = hbufR[ri][sL][k];
            o0 = fmaf(hk, rw1[wb1 + k * 16 + cq * 4 + 0], o0);
            o1 = fmaf(hk, rw1[wb1 + k * 16 + cq * 4 + 1], o1);
            o2 = fmaf(hk, rw1[wb1 + k * 16 + cq * 4 + 2], o2);
            o3 = fmaf(hk, rw1[wb1 + k * 16 + cq * 4 + 3], o3);
          }
          float v0 = fmaxf(fmaf(o0, rg1[cb + cq * 4 + 0] * kBNS, rb1[cb + cq * 4 + 0]), 0.f);
          float v1 = fmaxf(fmaf(o1, rg1[cb + cq * 4 + 1] * kBNS, rb1[cb + cq * 4 + 1]), 0.f);
          float v2 = fmaxf(fmaf(o2, rg1[cb + cq * 4 + 2] * kBNS, rb1[cb + cq * 4 + 2]), 0.f);
          float v3 = fmaxf(fmaf(o3, rg1[cb + cq * 4 + 3] * kBNS, rb1[cb + cq * 4 + 3]), 0.f);
#pragma unroll
          for (int off = 1; off < 16; off <<= 1) {
            v0 = fmaxf(v0, __shfl_xor(v0, off, 64));
            v1 = fmaxf(v1, __shfl_xor(v1, off, 64));
            v2 = fmaxf(v2, __shfl_xor(v2, off, 64));
            v3 = fmaxf(v3, __shfl_xor(v3, off, 64));
          }
          if (sL == 0) {
            featsL[outoff + cq * 4 + 0] = v0;
            featsL[outoff + cq * 4 + 1] = v1;
            featsL[outoff + cq * 4 + 2] = v2;
            featsL[outoff + cq * 4 + 3] = v3;
          }
        }
      } else if (wv < 4) {
        // ---- conv SA (identical math; weights from LDS), ri = wv-2 ----
        const int ri = wv - 2;
        const int NS = ri ? 32 : 16;
        const float R2 = ri ? (float)(2.4 * 2.4) : (float)(1.2 * 1.2);
        const int cbase = bb * MVOX;
        int cnt = 0;
        {
#pragma clang fp contract(off)
          for (int ch = 0; ch < MVOX / 64 && cnt < NS; ++ch) {
            const float4 q = cxyz4[cbase + ch * 64 + lane];
            float dx = kxv - q.x, dy = kyv - q.y, dz = kzv - q.z;
            float d2 = dx * dx; d2 = d2 + dy * dy; d2 = d2 + dz * dz;
            unsigned long long m = __ballot(d2 < R2);
            while (m && cnt < NS) {
              int bit = __builtin_ctzll(m);
              if (lane == 0) idxlC[ri][cnt] = ch * 64 + bit;
              ++cnt;
              m &= m - 1;
            }
          }
        }
        const int outoff = 288 + ri * 64;
        if (cnt == 0) {
          featsL[outoff + lane] = 0.f;
        } else {
          __threadfence_block();
          const float wA0 = ldsW0[(ri * 67 + 0) * 64 + lane];
          const float wA1 = ldsW0[(ri * 67 + 1) * 64 + lane];
          const float wA2 = ldsW0[(ri * 67 + 2) * 64 + lane];
          const float* wB = &ldsW0[(ri * 67 + 3) * 64 + lane];
          const float* wC = &ldsW1[ri * 64 * 64 + lane];
          const float s0 = cg0[ri * 64 + lane] * kBNS, bb0 = cb0[ri * 64 + lane];
          const float s1 = cg1[ri * 64 + lane] * kBNS, bb1 = cb1[ri * 64 + lane];
          for (int sm = 0; sm < cnt; ++sm) {
            const int p = cbase + idxlC[ri][sm];
            const float4 q = cxyz4[p];
            const float ox = q.x - kxv, oy = q.y - kyv, oz = q.z - kzv;
            gbuf[ri][lane] = vf[(size_t)p * 64 + lane];
            __threadfence_block();
            float acc = ox * wA0;
            acc = fmaf(oy, wA1, acc);
            acc = fmaf(oz, wA2, acc);
#pragma unroll
            for (int k4 = 0; k4 < 16; ++k4) {
              float4 g4 = *(const float4*)&gbuf[ri][k4 * 4];
              acc = fmaf(g4.x, wB[(k4 * 4 + 0) * 64], acc);
              acc = fmaf(g4.y, wB[(k4 * 4 + 1) * 64], acc);
              acc = fmaf(g4.z, wB[(k4 * 4 + 2) * 64], acc);
              acc = fmaf(g4.w, wB[(k4 * 4 + 3) * 64], acc);
            }
            hbufC[ri][sm][lane] = fmaxf(fmaf(acc, s0, bb0), 0.f);
            __threadfence_block();
          }
          float mx = -1e30f;
          for (int sm = 0; sm < cnt; ++sm) {
            float acc = 0.f;
#pragma unroll
            for (int k4 = 0; k4 < 16; ++k4) {
              float4 h4 = *(const float4*)&hbufC[ri][sm][k4 * 4];
              acc = fmaf(h4.x, wC[(k4 * 4 + 0) * 64], acc);
              acc = fmaf(h4.y, wC[(k4 * 4 + 1) * 64], acc);
              acc = fmaf(h4.z, wC[(k4 * 4 + 2) * 64], acc);
              acc = fmaf(h4.w, wC[(k4 * 4 + 3) * 64], acc);
            }
            mx = fmaxf(mx, fmaxf(fmaf(acc, s1, bb1), 0.f));
          }
          featsL[outoff + lane] = mx;
        }
      } else if (wv < 8) {
        // ---- BEV bilinear (identical math), c = t-256 ----
#pragma clang fp contract(off)
        const int c = t - 256;
        const float x = (kxv - 0.0f) / 0.05f / 8.0f;
        const float y = (kyv - (-40.0f)) / 0.05f / 8.0f;
        const float xf = floorf(x), yf = floorf(y);
        int x0 = (int)xf;     x0 = x0 < 0 ? 0 : (x0 > 175 ? 175 : x0);
        int x1 = (int)xf + 1; x1 = x1 < 0 ? 0 : (x1 > 175 ? 175 : x1);
        int y0 = (int)yf;     y0 = y0 < 0 ? 0 : (y0 > 199 ? 199 : y0);
        int y1 = (int)yf + 1; y1 = y1 < 0 ? 0 : (y1 > 199 ? 199 : y1);
        const float x0f = (float)x0, x1f = (float)x1, y0f = (float)y0, y1f = (float)y1;
        const float wa = (x - x0f) * (y1f - y);
        const float wbv = (x1f - x) * (y1f - y);
        const float wc = (x1f - x) * (y - y0f);
        const float wd = (x - x0f) * (y - y0f);
        const float* bsf = sf + ((size_t)bb * 256 + c) * (200 * 176);
        const float fa = bsf[y1 * 176 + x0];
        const float fbv = bsf[y1 * 176 + x1];
        const float fc = bsf[y0 * 176 + x1];
        const float fd = bsf[y0 * 176 + x0];
        float r = fd * wbv; r = r + fc * wa; r = r + fa * wc; r = r + fbv * wd;
        featsL[c] = r;
      }
      __syncthreads();

      // ---- fusion 416 -> 128 (identical math), c = t ----
      if (t < 128) {
        const int c = t;
        float acc = 0.f;
#pragma unroll 4
        for (int k = 0; k < 416; k += 4) {
          float4 fv = *(const float4*)(featsL + k);
          acc = fmaf(fv.x, fw[(k + 0) * 128 + c], acc);
          acc = fmaf(fv.y, fw[(k + 1) * 128 + c], acc);
          acc = fmaf(fv.z, fw[(k + 2) * 128 + c], acc);
          acc = fmaf(fv.w, fw[(k + 3) * 128 + c], acc);
        }
        out[(size_t)kidx * 128 + c] =
            fmaxf(fmaf(acc, fg[c] * kBNS, fb[c]), 0.f);
      }
      __syncthreads();   // featsL reused next keypoint
    }
  }
}

// ---------------------------------------------------------------------------
extern "C" void kernel_launch(void* const* d_in, const int* in_sizes, int n_in,
                              void* d_out, int out_size, void* d_ws, size_t ws_size,
                              hipStream_t stream) {
  (void)in_sizes; (void)n_in; (void)out_size; (void)ws_size;
  const float* pts = (const float*)d_in[0];
  const float* sf  = (const float*)d_in[1];
  const int*   vc  = (const int*)d_in[2];
  const float* vf  = (const float*)d_in[3];
  const float* raw_w0 = (const float*)d_in[4];
  const float* raw_g0 = (const float*)d_in[5];
  const float* raw_b0 = (const float*)d_in[6];
  const float* raw_w1 = (const float*)d_in[7];
  const float* raw_g1 = (const float*)d_in[8];
  const float* raw_b1 = (const float*)d_in[9];
  const float* conv_w0 = (const float*)d_in[10];
  const float* conv_g0 = (const float*)d_in[11];
  const float* conv_b0 = (const float*)d_in[12];
  const float* conv_w1 = (const float*)d_in[13];
  const float* conv_g1 = (const float*)d_in[14];
  const float* conv_b1 = (const float*)d_in[15];
  const float* fus_w = (const float*)d_in[16];
  const float* fus_g = (const float*)d_in[17];
  const float* fus_b = (const float*)d_in[18];
  float* out = (float*)d_out;

  float* W = (float*)d_ws;
  float4* xyz4  = (float4*)W;             // 32768 float4 = 131072 floats
  float4* cxyz4 = (float4*)(W + 131072);  // 16384 float4 = 65536 floats
  float* kx    = W + 196608;              // 4096 each
  float* ky    = W + 200704;
  float* kz    = W + 204800;
  int*   prog  = (int*)(W + 208896);      // 2 ints, zeroed per launch
  int*   sperm = (int*)(W + 209920);      // 32768 ints

  hipMemsetAsync(prog, 0, 2 * sizeof(int), stream);
  prep_kernel<<<128, 256, 0, stream>>>(pts, vc, xyz4, cxyz4);
  sort_kernel<<<2, 1024, 0, stream>>>(pts, sperm);
  fused_kernel<<<NBLK, 1024, 0, stream>>>(
      sperm, xyz4, cxyz4, vf, sf,
      raw_w0, raw_g0, raw_b0, raw_w1, raw_g1, raw_b1,
      conv_w0, conv_g0, conv_b0, conv_w1, conv_g1, conv_b1,
      fus_w, fus_g, fus_b, kx, ky, kz, prog, out);
}

// Round 9
// 3015.103 us; speedup vs baseline: 1.0399x; 1.0042x over previous
//
#include <hip/hip_runtime.h>

// ---------------------------------------------------------------------------
// VoxelSetAbstraction forward (PV-RCNN style) for MI355X
//   B=2, N_RAW=16384, N_KP=2048, M_VOX=8192, C_VOX=64
//   BEV: (2,256,200,176), stride 8, voxel 0.05, pc_min (0,-40,-3)
//   raw SA: radii (0.4,0.8) ns (16,16), MLP 4->16->16
//   conv SA: radii (1.2,2.4) ns (16,32), MLP 67->64->64
//   fusion: 416 -> 128
//
// r9: fused producer/consumer with ZERO cache-invalidating sync.
//   r8 evidence: traffic (439MB) and fps slowdown invariant to probe rate ->
//   the ACQUIRE's global_inv (full local-L2 invalidate per probe) was the
//   cost, not probe frequency. Fix: poll AND read kx/ky/kz with RELAXED
//   agent-scope atomics (L2-bypassing loads at the coherent point, NO inv).
//   Ordering: fps's RELEASE on prog global_wb-flushes its kx/ky/kz stores to
//   the coherent point before prog updates there; worker kx atomic loads
//   issue only after the poll observes prog>s and bypass local caches ->
//   they see the released values. Worker/fps L2s stay warm.
// Math byte-identical to r7/r8 (both passed verification).
// ---------------------------------------------------------------------------

#define NRAW    16384
#define MVOX    8192
#define NKP     2048
#define NKPALL  4096   // B * NKP
#define NWORKER 168    // included workers after XCD exclusion
#define NBLK    226    // 2 fps + 224 worker slots (56 exit immediately)

__device__ __constant__ float kBNS = (float)0.9999950000374997; // 1/sqrt(1+1e-5)

typedef float f32x2 __attribute__((ext_vector_type(2)));

// ---------------------------------------------------------------------------
// K0: pack points to interleaved float4 (x,y,z,intensity) + voxel centers
// ---------------------------------------------------------------------------
__global__ __launch_bounds__(256) void prep_kernel(
    const float* __restrict__ pts, const int* __restrict__ vc,
    float4* __restrict__ xyz4, float4* __restrict__ cxyz4) {
#pragma clang fp contract(off)
  int i = blockIdx.x * 256 + threadIdx.x;
  if (i < 2 * NRAW) {
    const float* p = pts + (size_t)i * 5;
    xyz4[i] = make_float4(p[1], p[2], p[3], p[4]);
  }
  if (i < 2 * MVOX) {
    const int* v = vc + (size_t)i * 4;
    cxyz4[i] = make_float4(((float)v[3] + 0.5f) * 0.2f + 0.0f,
                           ((float)v[2] + 0.5f) * 0.2f + -40.0f,
                           ((float)v[1] + 0.5f) * 0.4f + -3.0f, 0.f);
  }
}

// ---------------------------------------------------------------------------
// K0b: y-histogram sort (256 bins) per batch -> sperm (sorted-pos -> original
// local index). Proven-best y-slab binning (r0/r3/r4 A/B). FPS output is
// bin-order-invariant: ties resolved by ORIGINAL index carried in registers.
// ---------------------------------------------------------------------------
__global__ __launch_bounds__(1024) void sort_kernel(
    const float* __restrict__ pts, int* __restrict__ sperm) {
  const int b = blockIdx.x, t = threadIdx.x;
  __shared__ unsigned hist[256], cur[256];
  if (t < 256) hist[t] = 0u;
  __syncthreads();
  int bins[16];
#pragma unroll
  for (int k = 0; k < 16; ++k) {
    const int i = k * 1024 + t;
    const float y = pts[(size_t)(b * NRAW + i) * 5 + 2];
    int bin = (int)((y + 40.0f) * 3.2f);
    bin = bin < 0 ? 0 : (bin > 255 ? 255 : bin);
    bins[k] = bin;
    atomicAdd(&hist[bin], 1u);
  }
  __syncthreads();
  if (t == 0) {
    unsigned acc = 0;
    for (int i = 0; i < 256; ++i) { cur[i] = acc; acc += hist[i]; }
  }
  __syncthreads();
#pragma unroll
  for (int k = 0; k < 16; ++k) {
    const int i = k * 1024 + t;
    const unsigned pos = atomicAdd(&cur[bins[k]], 1u);
    sperm[b * NRAW + pos] = i;
  }
}

// Fused 64-bit DPP max-reduce stage (proven r6). After the 6-stage ladder the
// wave max of (hi:lo) lives in lane 63.
#define U64_STAGE(CTRL, RMASK)                                                 \
  {                                                                            \
    const unsigned tlo = (unsigned)__builtin_amdgcn_update_dpp(                \
        0, (int)lo, CTRL, RMASK, 0xf, true);                                   \
    const unsigned thi = (unsigned)__builtin_amdgcn_update_dpp(                \
        0, (int)hi, CTRL, RMASK, 0xf, true);                                   \
    const unsigned long long tv = ((unsigned long long)thi << 32) | tlo;       \
    const unsigned long long cv = ((unsigned long long)hi << 32) | lo;         \
    if (tv > cv) { hi = thi; lo = tlo; }                                       \
  }

// ---------------------------------------------------------------------------
// FUSED kernel: blocks 0,1 = fps (r6-identical math + periodic publish);
// included workers = per-keypoint consumers (bev + raw SA + conv SA + fusion).
// ---------------------------------------------------------------------------
__global__ __launch_bounds__(1024, 1) void fused_kernel(
    const int* __restrict__ sperm, const float4* __restrict__ xyz4,
    const float4* __restrict__ cxyz4, const float* __restrict__ vf,
    const float* __restrict__ sf,
    const float* __restrict__ rw0, const float* __restrict__ rg0,
    const float* __restrict__ rb0, const float* __restrict__ rw1,
    const float* __restrict__ rg1, const float* __restrict__ rb1,
    const float* __restrict__ cw0, const float* __restrict__ cg0,
    const float* __restrict__ cb0, const float* __restrict__ cw1,
    const float* __restrict__ cg1, const float* __restrict__ cb1,
    const float* __restrict__ fw, const float* __restrict__ fg,
    const float* __restrict__ fb,
    float* kx, float* ky, float* kz,
    int* prog, float* __restrict__ out) {
  const int t = threadIdx.x;
  const int wv = t >> 6, lane = t & 63;

  // ---- static LDS (86KB total -> forces 1 block/CU; grid 226 <= 256 CUs) ----
  __shared__ unsigned long long slot[3];                 // fps
  __shared__ float ldsW0[2 * 67 * 64];                   // conv w0 (34304B)
  __shared__ float ldsW1[2 * 64 * 64];                   // conv w1 (32768B)
  __shared__ int   idxlC[2][32];
  __shared__ __align__(16) float gbuf[2][64];
  __shared__ __align__(16) float hbufC[2][32][64];       // 16KB
  __shared__ int   idxlR[2][16];
  __shared__ float hbufR[2][16][17];
  __shared__ __align__(16) float featsL[416];
  __shared__ float kxyz[4];

  if (blockIdx.x < 2) {
    // =================== FPS (byte-identical r6 selection math) ===========
#pragma clang fp contract(off)
    const int b = blockIdx.x;
    const int wb = wv * 1024;
    const int base = b * NRAW;

    int pj[16];
    f32x2 px2[8], py2[8], pz2[8], dd2[8];
#pragma unroll
    for (int j = 0; j < 16; ++j)
      pj[j] = sperm[base + wb + j * 64 + lane];
#pragma unroll
    for (int j = 0; j < 16; ++j) {
      const float4 q = xyz4[base + pj[j]];  // gather; warms local L2
      px2[j >> 1][j & 1] = q.x;
      py2[j >> 1][j & 1] = q.y;
      pz2[j >> 1][j & 1] = q.z;
      dd2[j >> 1][j & 1] = 1e10f;
    }
    if (t < 3) slot[t] = 0ULL;

    float bnx = px2[0].x, bxx = px2[0].x, bny = py2[0].x, bxy = py2[0].x,
          bnz = pz2[0].x, bxz = pz2[0].x;
#pragma unroll
    for (int j = 1; j < 16; ++j) {
      bnx = fminf(bnx, px2[j >> 1][j & 1]); bxx = fmaxf(bxx, px2[j >> 1][j & 1]);
      bny = fminf(bny, py2[j >> 1][j & 1]); bxy = fmaxf(bxy, py2[j >> 1][j & 1]);
      bnz = fminf(bnz, pz2[j >> 1][j & 1]); bxz = fmaxf(bxz, pz2[j >> 1][j & 1]);
    }
#pragma unroll
    for (int off = 1; off < 64; off <<= 1) {
      bnx = fminf(bnx, __shfl_xor(bnx, off, 64));
      bxx = fmaxf(bxx, __shfl_xor(bxx, off, 64));
      bny = fminf(bny, __shfl_xor(bny, off, 64));
      bxy = fmaxf(bxy, __shfl_xor(bxy, off, 64));
      bnz = fminf(bnz, __shfl_xor(bnz, off, 64));
      bxz = fmaxf(bxz, __shfl_xor(bxz, off, 64));
    }

    const float4 p0 = xyz4[base];
    float lx = p0.x, ly = p0.y, lz = p0.z;
    if (t == 0) { kx[b * NKP] = lx; ky[b * NKP] = ly; kz[b * NKP] = lz; }

    unsigned long long cpk = 0ULL;
    float bvc = __builtin_inff();
    __syncthreads();

    for (int s = 1; s < NKP; ++s) {
      float dxm = fmaxf(fmaxf(bnx - lx, lx - bxx), 0.f);
      float dym = fmaxf(fmaxf(bny - ly, ly - bxy), 0.f);
      float dzm = fmaxf(fmaxf(bnz - lz, lz - bxz), 0.f);
      const float LB2 = dxm * dxm + dym * dym + dzm * dzm;
      if (!(LB2 * 0.9999f > bvc)) {       // active
        const f32x2 lx2 = {lx, lx}, ly2 = {ly, ly}, lz2 = {lz, lz};
#pragma unroll
        for (int j8 = 0; j8 < 8; ++j8) {
          f32x2 dx = px2[j8] - lx2;
          f32x2 dy = py2[j8] - ly2;
          f32x2 dz = pz2[j8] - lz2;
          f32x2 d2 = dx * dx;
          d2 = d2 + dy * dy;
          d2 = d2 + dz * dz;
          dd2[j8] = __builtin_elementwise_min(dd2[j8], d2);
        }
        f32x2 t0 = __builtin_elementwise_max(dd2[0], dd2[1]);
        f32x2 t1 = __builtin_elementwise_max(dd2[2], dd2[3]);
        f32x2 t2 = __builtin_elementwise_max(dd2[4], dd2[5]);
        f32x2 t3 = __builtin_elementwise_max(dd2[6], dd2[7]);
        t0 = __builtin_elementwise_max(t0, t1);
        t2 = __builtin_elementwise_max(t2, t3);
        t0 = __builtin_elementwise_max(t0, t2);
        const float bv = fmaxf(t0.x, t0.y);
        const unsigned vb = __float_as_uint(bv);
        unsigned mo = 0xFFFFFFFFu;
#pragma unroll
        for (int j = 0; j < 16; ++j)
          if (__float_as_uint(dd2[j >> 1][j & 1]) == vb) {
            const unsigned o = (unsigned)pj[j];
            mo = o < mo ? o : mo;
          }
        unsigned hi = vb, lo = ~mo;
        U64_STAGE(0xB1,  0xf)
        U64_STAGE(0x4E,  0xf)
        U64_STAGE(0x124, 0xf)
        U64_STAGE(0x128, 0xf)
        U64_STAGE(0x142, 0xa)
        U64_STAGE(0x143, 0xc)
        bvc = __uint_as_float(
            (unsigned)__builtin_amdgcn_readlane((int)hi, 63));
        cpk = ((unsigned long long)hi << 32) | (unsigned long long)lo;
      }
      if (lane == 63) atomicMax(&slot[s % 3], cpk);
      __syncthreads();

      const unsigned long long g = slot[s % 3];
      const int wi = __builtin_amdgcn_readfirstlane((int)~(unsigned)g);
      if (t == 0) slot[(s + 2) % 3] = 0ULL;
      const float4 cw = xyz4[base + wi];
      lx = cw.x; ly = cw.y; lz = cw.z;
      if (t == 0) {
        kx[b * NKP + s] = lx; ky[b * NKP + s] = ly; kz[b * NKP + s] = lz;
        if ((s & 15) == 15)   // publish 16 keypoints; RELEASE global_wb
          __hip_atomic_store(&prog[b], s + 1, __ATOMIC_RELEASE,
                             __HIP_MEMORY_SCOPE_AGENT);
      }
    }
  } else {
    // =================== WORKER: one keypoint per pass =====================
    const int bi = (int)blockIdx.x;
    const int sub = bi & 7;
    if (sub < 2) return;   // heuristic: keep fps blocks' XCDs capacity-clean
    const int wkr = (bi >> 3) * 6 + (sub - 2);   // 0..167

    // stage conv weights to LDS once (values identical to global)
    for (int i = t; i < 2 * 67 * 64; i += 1024) ldsW0[i] = cw0[i];
    for (int i = t; i < 2 * 64 * 64; i += 1024) ldsW1[i] = cw1[i];
    __syncthreads();

    for (int g = wkr; g < NKPALL; g += NWORKER) {
      const int bb = g >> 11, s = g & 2047;
      const int kidx = g;
      if (t == 0) {
        // RELAXED poll: L2-bypassing coherent-point load, NO global_inv.
        while (__hip_atomic_load(&prog[bb], __ATOMIC_RELAXED,
                                 __HIP_MEMORY_SCOPE_AGENT) <= s)
          __builtin_amdgcn_s_sleep(127);
        // RELAXED atomic coord reads: bypass local caches, see the data the
        // producer's RELEASE(global_wb) pushed to the coherent point.
        kxyz[0] = __hip_atomic_load(&kx[kidx], __ATOMIC_RELAXED,
                                    __HIP_MEMORY_SCOPE_AGENT);
        kxyz[1] = __hip_atomic_load(&ky[kidx], __ATOMIC_RELAXED,
                                    __HIP_MEMORY_SCOPE_AGENT);
        kxyz[2] = __hip_atomic_load(&kz[kidx], __ATOMIC_RELAXED,
                                    __HIP_MEMORY_SCOPE_AGENT);
      }
      __syncthreads();
      const float kxv = kxyz[0], kyv = kxyz[1], kzv = kxyz[2];

      if (wv < 2) {
        // ---- raw SA (identical math to raw_sa_kernel), ri = wv ----
        const int ri = wv;
        const float R2 = ri ? (float)(0.8 * 0.8) : (float)(0.4 * 0.4);
        const int rbase = bb * NRAW;
        int cnt = 0;
        {
#pragma clang fp contract(off)
          for (int ch = 0; ch < NRAW / 64 && cnt < 16; ++ch) {
            const float4 q = xyz4[rbase + ch * 64 + lane];
            float dx = kxv - q.x, dy = kyv - q.y, dz = kzv - q.z;
            float d2 = dx * dx; d2 = d2 + dy * dy; d2 = d2 + dz * dz;
            unsigned long long m = __ballot(d2 < R2);
            while (m && cnt < 16) {
              int bit = __builtin_ctzll(m);
              if (lane == 0) idxlR[ri][cnt] = ch * 64 + bit;
              ++cnt;
              m &= m - 1;
            }
          }
        }
        const int outoff = 256 + ri * 16;
        if (cnt == 0) {
          if (lane < 16) featsL[outoff + lane] = 0.f;
        } else {
          __threadfence_block();
          const int sL = lane & 15, cq = lane >> 4;
          const int ss = (sL < cnt) ? sL : 0;
          const float4 q = xyz4[rbase + idxlR[ri][ss]];
          const float gx = q.x - kxv, gy = q.y - kyv, gz = q.z - kzv, gi = q.w;
          const int wb0 = ri * 64, cb = ri * 16;
#pragma unroll
          for (int j = 0; j < 4; ++j) {
            int c = cq * 4 + j;
            float a = gx * rw0[wb0 + c];
            a = fmaf(gy, rw0[wb0 + 16 + c], a);
            a = fmaf(gz, rw0[wb0 + 32 + c], a);
            a = fmaf(gi, rw0[wb0 + 48 + c], a);
            a = fmaf(a, rg0[cb + c] * kBNS, rb0[cb + c]);
            hbufR[ri][sL][c] = fmaxf(a, 0.f);
          }
          __threadfence_block();
          float o0 = 0.f, o1 = 0.f, o2 = 0.f, o3 = 0.f;
          const int wb1 = ri * 256;
#pragma unroll
          for (int k = 0; k < 16; ++k) {
            float hk = hbufR[ri][sL][k];
            o0 = fmaf(hk, rw1[wb1 + k * 16 + cq * 4 + 0], o0);
            o1 = fmaf(hk, rw1[wb1 + k * 16 + cq * 4 + 1], o1);
            o2 = fmaf(hk, rw1[wb1 + k * 16 + cq * 4 + 2], o2);
            o3 = fmaf(hk, rw1[wb1 + k * 16 + cq * 4 + 3], o3);
          }
          float v0 = fmaxf(fmaf(o0, rg1[cb + cq * 4 + 0] * kBNS, rb1[cb + cq * 4 + 0]), 0.f);
          float v1 = fmaxf(fmaf(o1, rg1[cb + cq * 4 + 1] * kBNS, rb1[cb + cq * 4 + 1]), 0.f);
          float v2 = fmaxf(fmaf(o2, rg1[cb + cq * 4 + 2] * kBNS, rb1[cb + cq * 4 + 2]), 0.f);
          float v3 = fmaxf(fmaf(o3, rg1[cb + cq * 4 + 3] * kBNS, rb1[cb + cq * 4 + 3]), 0.f);
#pragma unroll
          for (int off = 1; off < 16; off <<= 1) {
            v0 = fmaxf(v0, __shfl_xor(v0, off, 64));
            v1 = fmaxf(v1, __shfl_xor(v1, off, 64));
            v2 = fmaxf(v2, __shfl_xor(v2, off, 64));
            v3 = fmaxf(v3, __shfl_xor(v3, off, 64));
          }
          if (sL == 0) {
            featsL[outoff + cq * 4 + 0] = v0;
            featsL[outoff + cq * 4 + 1] = v1;
            featsL[outoff + cq * 4 + 2] = v2;
            featsL[outoff + cq * 4 + 3] = v3;
          }
        }
      } else if (wv < 4) {
        // ---- conv SA (identical math; weights from LDS), ri = wv-2 ----
        const int ri = wv - 2;
        const int NS = ri ? 32 : 16;
        const float R2 = ri ? (float)(2.4 * 2.4) : (float)(1.2 * 1.2);
        const int cbase = bb * MVOX;
        int cnt = 0;
        {
#pragma clang fp contract(off)
          for (int ch = 0; ch < MVOX / 64 && cnt < NS; ++ch) {
            const float4 q = cxyz4[cbase + ch * 64 + lane];
            float dx = kxv - q.x, dy = kyv - q.y, dz = kzv - q.z;
            float d2 = dx * dx; d2 = d2 + dy * dy; d2 = d2 + dz * dz;
            unsigned long long m = __ballot(d2 < R2);
            while (m && cnt < NS) {
              int bit = __builtin_ctzll(m);
              if (lane == 0) idxlC[ri][cnt] = ch * 64 + bit;
              ++cnt;
              m &= m - 1;
            }
          }
        }
        const int outoff = 288 + ri * 64;
        if (cnt == 0) {
          featsL[outoff + lane] = 0.f;
        } else {
          __threadfence_block();
          const float wA0 = ldsW0[(ri * 67 + 0) * 64 + lane];
          const float wA1 = ldsW0[(ri * 67 + 1) * 64 + lane];
          const float wA2 = ldsW0[(ri * 67 + 2) * 64 + lane];
          const float* wB = &ldsW0[(ri * 67 + 3) * 64 + lane];
          const float* wC = &ldsW1[ri * 64 * 64 + lane];
          const float s0 = cg0[ri * 64 + lane] * kBNS, bb0 = cb0[ri * 64 + lane];
          const float s1 = cg1[ri * 64 + lane] * kBNS, bb1 = cb1[ri * 64 + lane];
          for (int sm = 0; sm < cnt; ++sm) {
            const int p = cbase + idxlC[ri][sm];
            const float4 q = cxyz4[p];
            const float ox = q.x - kxv, oy = q.y - kyv, oz = q.z - kzv;
            gbuf[ri][lane] = vf[(size_t)p * 64 + lane];
            __threadfence_block();
            float acc = ox * wA0;
            acc = fmaf(oy, wA1, acc);
            acc = fmaf(oz, wA2, acc);
#pragma unroll
            for (int k4 = 0; k4 < 16; ++k4) {
              float4 g4 = *(const float4*)&gbuf[ri][k4 * 4];
              acc = fmaf(g4.x, wB[(k4 * 4 + 0) * 64], acc);
              acc = fmaf(g4.y, wB[(k4 * 4 + 1) * 64], acc);
              acc = fmaf(g4.z, wB[(k4 * 4 + 2) * 64], acc);
              acc = fmaf(g4.w, wB[(k4 * 4 + 3) * 64], acc);
            }
            hbufC[ri][sm][lane] = fmaxf(fmaf(acc, s0, bb0), 0.f);
            __threadfence_block();
          }
          float mx = -1e30f;
          for (int sm = 0; sm < cnt; ++sm) {
            float acc = 0.f;
#pragma unroll
            for (int k4 = 0; k4 < 16; ++k4) {
              float4 h4 = *(const float4*)&hbufC[ri][sm][k4 * 4];
              acc = fmaf(h4.x, wC[(k4 * 4 + 0) * 64], acc);
              acc = fmaf(h4.y, wC[(k4 * 4 + 1) * 64], acc);
              acc = fmaf(h4.z, wC[(k4 * 4 + 2) * 64], acc);
              acc = fmaf(h4.w, wC[(k4 * 4 + 3) * 64], acc);
            }
            mx = fmaxf(mx, fmaxf(fmaf(acc, s1, bb1), 0.f));
          }
          featsL[outoff + lane] = mx;
        }
      } else if (wv < 8) {
        // ---- BEV bilinear (identical math), c = t-256 ----
#pragma clang fp contract(off)
        const int c = t - 256;
        const float x = (kxv - 0.0f) / 0.05f / 8.0f;
        const float y = (kyv - (-40.0f)) / 0.05f / 8.0f;
        const float xf = floorf(x), yf = floorf(y);
        int x0 = (int)xf;     x0 = x0 < 0 ? 0 : (x0 > 175 ? 175 : x0);
        int x1 = (int)xf + 1; x1 = x1 < 0 ? 0 : (x1 > 175 ? 175 : x1);
        int y0 = (int)yf;     y0 = y0 < 0 ? 0 : (y0 > 199 ? 199 : y0);
        int y1 = (int)yf + 1; y1 = y1 < 0 ? 0 : (y1 > 199 ? 199 : y1);
        const float x0f = (float)x0, x1f = (float)x1, y0f = (float)y0, y1f = (float)y1;
        const float wa = (x - x0f) * (y1f - y);
        const float wbv = (x1f - x) * (y1f - y);
        const float wc = (x1f - x) * (y - y0f);
        const float wd = (x - x0f) * (y - y0f);
        const float* bsf = sf + ((size_t)bb * 256 + c) * (200 * 176);
        const float fa = bsf[y1 * 176 + x0];
        const float fbv = bsf[y1 * 176 + x1];
        const float fc = bsf[y0 * 176 + x1];
        const float fd = bsf[y0 * 176 + x0];
        float r = fd * wbv; r = r + fc * wa; r = r + fa * wc; r = r + fbv * wd;
        featsL[c] = r;
      }
      __syncthreads();

      // ---- fusion 416 -> 128 (identical math), c = t ----
      if (t < 128) {
        const int c = t;
        float acc = 0.f;
#pragma unroll 4
        for (int k = 0; k < 416; k += 4) {
          float4 fv = *(const float4*)(featsL + k);
          acc = fmaf(fv.x, fw[(k + 0) * 128 + c], acc);
          acc = fmaf(fv.y, fw[(k + 1) * 128 + c], acc);
          acc = fmaf(fv.z, fw[(k + 2) * 128 + c], acc);
          acc = fmaf(fv.w, fw[(k + 3) * 128 + c], acc);
        }
        out[(size_t)kidx * 128 + c] =
            fmaxf(fmaf(acc, fg[c] * kBNS, fb[c]), 0.f);
      }
      __syncthreads();   // featsL reused next keypoint
    }
  }
}

// ---------------------------------------------------------------------------
extern "C" void kernel_launch(void* const* d_in, const int* in_sizes, int n_in,
                              void* d_out, int out_size, void* d_ws, size_t ws_size,
                              hipStream_t stream) {
  (void)in_sizes; (void)n_in; (void)out_size; (void)ws_size;
  const float* pts = (const float*)d_in[0];
  const float* sf  = (const float*)d_in[1];
  const int*   vc  = (const int*)d_in[2];
  const float* vf  = (const float*)d_in[3];
  const float* raw_w0 = (const float*)d_in[4];
  const float* raw_g0 = (const float*)d_in[5];
  const float* raw_b0 = (const float*)d_in[6];
  const float* raw_w1 = (const float*)d_in[7];
  const float* raw_g1 = (const float*)d_in[8];
  const float* raw_b1 = (const float*)d_in[9];
  const float* conv_w0 = (const float*)d_in[10];
  const float* conv_g0 = (const float*)d_in[11];
  const float* conv_b0 = (const float*)d_in[12];
  const float* conv_w1 = (const float*)d_in[13];
  const float* conv_g1 = (const float*)d_in[14];
  const float* conv_b1 = (const float*)d_in[15];
  const float* fus_w = (const float*)d_in[16];
  const float* fus_g = (const float*)d_in[17];
  const float* fus_b = (const float*)d_in[18];
  float* out = (float*)d_out;

  float* W = (float*)d_ws;
  float4* xyz4  = (float4*)W;             // 32768 float4 = 131072 floats
  float4* cxyz4 = (float4*)(W + 131072);  // 16384 float4 = 65536 floats
  float* kx    = W + 196608;              // 4096 each
  float* ky    = W + 200704;
  float* kz    = W + 204800;
  int*   prog  = (int*)(W + 208896);      // 2 ints, zeroed per launch
  int*   sperm = (int*)(W + 209920);      // 32768 ints

  hipMemsetAsync(prog, 0, 2 * sizeof(int), stream);
  prep_kernel<<<128, 256, 0, stream>>>(pts, vc, xyz4, cxyz4);
  sort_kernel<<<2, 1024, 0, stream>>>(pts, sperm);
  fused_kernel<<<NBLK, 1024, 0, stream>>>(
      sperm, xyz4, cxyz4, vf, sf,
      raw_w0, raw_g0, raw_b0, raw_w1, raw_g1, raw_b1,
      conv_w0, conv_g0, conv_b0, conv_w1, conv_g1, conv_b1,
      fus_w, fus_g, fus_b, kx, ky, kz, prog, out);
}

// Round 10
// 2554.940 us; speedup vs baseline: 1.2272x; 1.1801x over previous
//
#include <hip/hip_runtime.h>

// ---------------------------------------------------------------------------
// VoxelSetAbstraction forward (PV-RCNN style) for MI355X
//   B=2, N_RAW=16384, N_KP=2048, M_VOX=8192, C_VOX=64
//   BEV: (2,256,200,176), stride 8, voxel 0.05, pc_min (0,-40,-3)
//   raw SA: radii (0.4,0.8) ns (16,16), MLP 4->16->16
//   conv SA: radii (1.2,2.4) ns (16,32), MLP 67->64->64
//   fusion: 416 -> 128
//
// r10: REVERT to the proven split pipeline (r6, 2198us) after three fused
// designs all regressed (r7/r8/r9: 2886-3050us; worker co-residency dilates
// fps's latency-critical serial chain by more than the downstream is worth).
// Downstream consolidated: ONE post_kernel (4096 blocks = 1/keypoint) doing
// bev + raw SA + conv SA + fusion with LDS feats (math op-for-op identical
// to the r6 kernels), and prep merged into sort. 3 dispatches total.
// ---------------------------------------------------------------------------

#define NRAW   16384
#define MVOX   8192
#define NKP    2048
#define NKPALL 4096   // B * NKP

__device__ __constant__ float kBNS = (float)0.9999950000374997; // 1/sqrt(1+1e-5)

typedef float f32x2 __attribute__((ext_vector_type(2)));

// ---------------------------------------------------------------------------
// K0: per-batch pack (xyz4 / cxyz4) + y-histogram sort (256 bins) -> sperm.
// Pack math identical to the old prep_kernel (contract off); sort identical
// to the proven y-slab sort (r0/r3/r4 A/B best). Bin-internal order is
// nondeterministic (atomic ranks) but FPS output is order-invariant: ties
// are resolved by ORIGINAL index carried in registers.
// ---------------------------------------------------------------------------
__global__ __launch_bounds__(1024) void sort_prep_kernel(
    const float* __restrict__ pts, const int* __restrict__ vc,
    float4* __restrict__ xyz4, float4* __restrict__ cxyz4,
    int* __restrict__ sperm) {
#pragma clang fp contract(off)
  const int b = blockIdx.x, t = threadIdx.x;
  // pack this batch's points + voxel centers
  for (int i = t; i < NRAW; i += 1024) {
    const float* p = pts + (size_t)(b * NRAW + i) * 5;
    xyz4[b * NRAW + i] = make_float4(p[1], p[2], p[3], p[4]);
  }
  for (int i = t; i < MVOX; i += 1024) {
    const int* v = vc + (size_t)(b * MVOX + i) * 4;
    cxyz4[b * MVOX + i] = make_float4(((float)v[3] + 0.5f) * 0.2f + 0.0f,
                                      ((float)v[2] + 0.5f) * 0.2f + -40.0f,
                                      ((float)v[1] + 0.5f) * 0.4f + -3.0f, 0.f);
  }

  __shared__ unsigned hist[256], cur[256];
  if (t < 256) hist[t] = 0u;
  __syncthreads();
  int bins[16];
#pragma unroll
  for (int k = 0; k < 16; ++k) {
    const int i = k * 1024 + t;
    const float y = pts[(size_t)(b * NRAW + i) * 5 + 2];
    int bin = (int)((y + 40.0f) * 3.2f);
    bin = bin < 0 ? 0 : (bin > 255 ? 255 : bin);
    bins[k] = bin;
    atomicAdd(&hist[bin], 1u);
  }
  __syncthreads();
  if (t == 0) {
    unsigned acc = 0;
    for (int i = 0; i < 256; ++i) { cur[i] = acc; acc += hist[i]; }
  }
  __syncthreads();
#pragma unroll
  for (int k = 0; k < 16; ++k) {
    const int i = k * 1024 + t;
    const unsigned pos = atomicAdd(&cur[bins[k]], 1u);
    sperm[b * NRAW + pos] = i;
  }
}

// Fused 64-bit DPP max-reduce stage (proven r6). After the 6-stage ladder the
// wave max of (hi:lo) lives in lane 63.
#define U64_STAGE(CTRL, RMASK)                                                 \
  {                                                                            \
    const unsigned tlo = (unsigned)__builtin_amdgcn_update_dpp(                \
        0, (int)lo, CTRL, RMASK, 0xf, true);                                   \
    const unsigned thi = (unsigned)__builtin_amdgcn_update_dpp(                \
        0, (int)hi, CTRL, RMASK, 0xf, true);                                   \
    const unsigned long long tv = ((unsigned long long)thi << 32) | tlo;       \
    const unsigned long long cv = ((unsigned long long)hi << 32) | lo;         \
    if (tv > cv) { hi = thi; lo = tlo; }                                       \
  }

// ---------------------------------------------------------------------------
// K1: farthest point sampling -- byte-identical to the proven r6 version
// (1694us isolated): packed f32x2 dd-update, packed max tree, lane-local tie
// scan, single fused u64 DPP reduce, triple-buffered LDS atomicMax slot,
// uniform L2-warm winner s_load.
// ---------------------------------------------------------------------------
__global__ __launch_bounds__(1024, 4) void fps_kernel(
    const int* __restrict__ sperm, const float4* __restrict__ xyz4,
    float* __restrict__ kx, float* __restrict__ ky, float* __restrict__ kz) {
#pragma clang fp contract(off)
  const int b = blockIdx.x;
  const int t = threadIdx.x;
  const int w = t >> 6, lane = t & 63;
  const int wb = w * 1024;
  const int base = b * NRAW;

  __shared__ unsigned long long slot[3];

  int pj[16];
  f32x2 px2[8], py2[8], pz2[8], dd2[8];
#pragma unroll
  for (int j = 0; j < 16; ++j)
    pj[j] = sperm[base + wb + j * 64 + lane];
#pragma unroll
  for (int j = 0; j < 16; ++j) {
    const float4 q = xyz4[base + pj[j]];   // gather; warms local L2 with batch
    px2[j >> 1][j & 1] = q.x;
    py2[j >> 1][j & 1] = q.y;
    pz2[j >> 1][j & 1] = q.z;
    dd2[j >> 1][j & 1] = 1e10f;
  }
  if (t < 3) slot[t] = 0ULL;

  // wave bbox (one-time): per-lane min/max then 6-stage shuffle reduce
  float bnx = px2[0].x, bxx = px2[0].x, bny = py2[0].x, bxy = py2[0].x,
        bnz = pz2[0].x, bxz = pz2[0].x;
#pragma unroll
  for (int j = 1; j < 16; ++j) {
    bnx = fminf(bnx, px2[j >> 1][j & 1]); bxx = fmaxf(bxx, px2[j >> 1][j & 1]);
    bny = fminf(bny, py2[j >> 1][j & 1]); bxy = fmaxf(bxy, py2[j >> 1][j & 1]);
    bnz = fminf(bnz, pz2[j >> 1][j & 1]); bxz = fmaxf(bxz, pz2[j >> 1][j & 1]);
  }
#pragma unroll
  for (int off = 1; off < 64; off <<= 1) {
    bnx = fminf(bnx, __shfl_xor(bnx, off, 64));
    bxx = fmaxf(bxx, __shfl_xor(bxx, off, 64));
    bny = fminf(bny, __shfl_xor(bny, off, 64));
    bxy = fmaxf(bxy, __shfl_xor(bxy, off, 64));
    bnz = fminf(bnz, __shfl_xor(bnz, off, 64));
    bxz = fmaxf(bxz, __shfl_xor(bxz, off, 64));
  }

  const float4 p0 = xyz4[base];           // first keypoint = original idx 0
  float lx = p0.x, ly = p0.y, lz = p0.z;
  if (t == 0) { kx[b * NKP] = lx; ky[b * NKP] = ly; kz[b * NKP] = lz; }

  unsigned long long cpk = 0ULL;          // cached (val<<32 | ~minidx), lane63
  float bvc = __builtin_inff();           // cached wave max dd (inf: no skip)
  __syncthreads();

  for (int s = 1; s < NKP; ++s) {
    // conservative lower bound of d2 from center to any point of this wave
    float dxm = fmaxf(fmaxf(bnx - lx, lx - bxx), 0.f);
    float dym = fmaxf(fmaxf(bny - ly, ly - bxy), 0.f);
    float dzm = fmaxf(fmaxf(bnz - lz, lz - bxz), 0.f);
    const float LB2 = dxm * dxm + dym * dym + dzm * dzm;
    if (!(LB2 * 0.9999f > bvc)) {         // active
      const f32x2 lx2 = {lx, lx}, ly2 = {ly, ly}, lz2 = {lz, lz};
#pragma unroll
      for (int j8 = 0; j8 < 8; ++j8) {    // packed: 2 points per op
        f32x2 dx = px2[j8] - lx2;
        f32x2 dy = py2[j8] - ly2;
        f32x2 dz = pz2[j8] - lz2;
        f32x2 d2 = dx * dx;
        d2 = d2 + dy * dy;
        d2 = d2 + dz * dz;
        dd2[j8] = __builtin_elementwise_min(dd2[j8], d2);
      }
      // packed max tree (max is exact & associative -> order-invariant)
      f32x2 t0 = __builtin_elementwise_max(dd2[0], dd2[1]);
      f32x2 t1 = __builtin_elementwise_max(dd2[2], dd2[3]);
      f32x2 t2 = __builtin_elementwise_max(dd2[4], dd2[5]);
      f32x2 t3 = __builtin_elementwise_max(dd2[6], dd2[7]);
      t0 = __builtin_elementwise_max(t0, t1);
      t2 = __builtin_elementwise_max(t2, t3);
      t0 = __builtin_elementwise_max(t0, t2);
      const float bv = fmaxf(t0.x, t0.y);
      const unsigned vb = __float_as_uint(bv);
      // lane-local min ORIGINAL idx among this lane's entries tied with bv
      unsigned mo = 0xFFFFFFFFu;
#pragma unroll
      for (int j = 0; j < 16; ++j)
        if (__float_as_uint(dd2[j >> 1][j & 1]) == vb) {
          const unsigned o = (unsigned)pj[j];
          mo = o < mo ? o : mo;
        }
      // single fused u64 DPP reduce: (max bv, then min original idx)
      unsigned hi = vb, lo = ~mo;
      U64_STAGE(0xB1,  0xf)
      U64_STAGE(0x4E,  0xf)
      U64_STAGE(0x124, 0xf)
      U64_STAGE(0x128, 0xf)
      U64_STAGE(0x142, 0xa)
      U64_STAGE(0x143, 0xc)
      bvc = __uint_as_float(
          (unsigned)__builtin_amdgcn_readlane((int)hi, 63));
      cpk = ((unsigned long long)hi << 32) | (unsigned long long)lo;
    }
    if (lane == 63) atomicMax(&slot[s % 3], cpk);
    __syncthreads();

    const unsigned long long g = slot[s % 3];
    const int wi = __builtin_amdgcn_readfirstlane((int)~(unsigned)g);
    if (t == 0) slot[(s + 2) % 3] = 0ULL;     // next used at iter s+2
    const float4 cw = xyz4[base + wi];        // uniform s_load, L2-warm
    lx = cw.x; ly = cw.y; lz = cw.z;
    if (t == 0) { kx[b * NKP + s] = lx; ky[b * NKP + s] = ly; kz[b * NKP + s] = lz; }
  }
}

// ---------------------------------------------------------------------------
// K2: merged per-keypoint downstream. One block per keypoint, 256 threads
// (4 waves). Phase A: all threads BEV (c = t). Phase B: waves 0-1 raw SA
// (ri = wv), waves 2-3 conv SA (ri = wv-2, register-resident weights exactly
// as the split conv kernel). Barrier. Phase C: threads 0-127 fusion from
// LDS featsL. All math op-for-op identical to the r6 split kernels; feats
// merely lives in LDS instead of global (same values, same op order).
// ---------------------------------------------------------------------------
__global__ __launch_bounds__(256) void post_kernel(
    const float4* __restrict__ xyz4, const float4* __restrict__ cxyz4,
    const float* __restrict__ vf, const float* __restrict__ sf,
    const float* __restrict__ rw0, const float* __restrict__ rg0,
    const float* __restrict__ rb0, const float* __restrict__ rw1,
    const float* __restrict__ rg1, const float* __restrict__ rb1,
    const float* __restrict__ cw0, const float* __restrict__ cg0,
    const float* __restrict__ cb0, const float* __restrict__ cw1,
    const float* __restrict__ cg1, const float* __restrict__ cb1,
    const float* __restrict__ fw, const float* __restrict__ fg,
    const float* __restrict__ fb,
    const float* __restrict__ kx, const float* __restrict__ ky,
    const float* __restrict__ kz, float* __restrict__ out) {
  const int kidx = blockIdx.x;
  const int bb = kidx >> 11;
  const int t = threadIdx.x;
  const int wv = t >> 6, lane = t & 63;

  __shared__ int   idxlR[2][16];
  __shared__ float hbufR[2][16][17];
  __shared__ int   idxlC[2][32];
  __shared__ __align__(16) float gbuf[2][64];
  __shared__ __align__(16) float hbufC[2][32][64];
  __shared__ __align__(16) float featsL[416];

  const float kxv = kx[kidx], kyv = ky[kidx], kzv = kz[kidx];

  // ---- Phase A: BEV bilinear (identical math), c = t ----
  {
#pragma clang fp contract(off)
    const int c = t;
    const float x = (kxv - 0.0f) / 0.05f / 8.0f;
    const float y = (kyv - (-40.0f)) / 0.05f / 8.0f;
    const float xf = floorf(x), yf = floorf(y);
    int x0 = (int)xf;     x0 = x0 < 0 ? 0 : (x0 > 175 ? 175 : x0);
    int x1 = (int)xf + 1; x1 = x1 < 0 ? 0 : (x1 > 175 ? 175 : x1);
    int y0 = (int)yf;     y0 = y0 < 0 ? 0 : (y0 > 199 ? 199 : y0);
    int y1 = (int)yf + 1; y1 = y1 < 0 ? 0 : (y1 > 199 ? 199 : y1);
    const float x0f = (float)x0, x1f = (float)x1, y0f = (float)y0, y1f = (float)y1;
    const float wa = (x - x0f) * (y1f - y);
    const float wbv = (x1f - x) * (y1f - y);
    const float wc = (x1f - x) * (y - y0f);
    const float wd = (x - x0f) * (y - y0f);
    const float* bsf = sf + ((size_t)bb * 256 + c) * (200 * 176);
    const float fa = bsf[y1 * 176 + x0];
    const float fbv = bsf[y1 * 176 + x1];
    const float fc = bsf[y0 * 176 + x1];
    const float fd = bsf[y0 * 176 + x0];
    float r = fd * wbv; r = r + fc * wa; r = r + fa * wc; r = r + fbv * wd;
    featsL[c] = r;
  }

  // ---- Phase B ----
  if (wv < 2) {
    // raw SA (identical math to r6 raw_sa_kernel), ri = wv
    const int ri = wv;
    const float R2 = ri ? (float)(0.8 * 0.8) : (float)(0.4 * 0.4);
    const int rbase = bb * NRAW;
    int cnt = 0;
    {
#pragma clang fp contract(off)
      for (int ch = 0; ch < NRAW / 64 && cnt < 16; ++ch) {
        const float4 q = xyz4[rbase + ch * 64 + lane];
        float dx = kxv - q.x, dy = kyv - q.y, dz = kzv - q.z;
        float d2 = dx * dx; d2 = d2 + dy * dy; d2 = d2 + dz * dz;
        unsigned long long m = __ballot(d2 < R2);
        while (m && cnt < 16) {
          int bit = __builtin_ctzll(m);
          if (lane == 0) idxlR[ri][cnt] = ch * 64 + bit;
          ++cnt;
          m &= m - 1;
        }
      }
    }
    const int outoff = 256 + ri * 16;
    if (cnt == 0) {
      if (lane < 16) featsL[outoff + lane] = 0.f;
    } else {
      __threadfence_block();
      const int sL = lane & 15, cq = lane >> 4;
      const int ss = (sL < cnt) ? sL : 0;    // duplicate sample 0 (ref pad)
      const float4 q = xyz4[rbase + idxlR[ri][ss]];
      const float gx = q.x - kxv, gy = q.y - kyv, gz = q.z - kzv, gi = q.w;
      const int wb0 = ri * 64, cb = ri * 16;
#pragma unroll
      for (int j = 0; j < 4; ++j) {
        int c = cq * 4 + j;
        float a = gx * rw0[wb0 + c];
        a = fmaf(gy, rw0[wb0 + 16 + c], a);
        a = fmaf(gz, rw0[wb0 + 32 + c], a);
        a = fmaf(gi, rw0[wb0 + 48 + c], a);
        a = fmaf(a, rg0[cb + c] * kBNS, rb0[cb + c]);
        hbufR[ri][sL][c] = fmaxf(a, 0.f);
      }
      __threadfence_block();
      float o0 = 0.f, o1 = 0.f, o2 = 0.f, o3 = 0.f;
      const int wb1 = ri * 256;
#pragma unroll
      for (int k = 0; k < 16; ++k) {
        float hk = hbufR[ri][sL][k];
        o0 = fmaf(hk, rw1[wb1 + k * 16 + cq * 4 + 0], o0);
        o1 = fmaf(hk, rw1[wb1 + k * 16 + cq * 4 + 1], o1);
        o2 = fmaf(hk, rw1[wb1 + k * 16 + cq * 4 + 2], o2);
        o3 = fmaf(hk, rw1[wb1 + k * 16 + cq * 4 + 3], o3);
      }
      float v0 = fmaxf(fmaf(o0, rg1[cb + cq * 4 + 0] * kBNS, rb1[cb + cq * 4 + 0]), 0.f);
      float v1 = fmaxf(fmaf(o1, rg1[cb + cq * 4 + 1] * kBNS, rb1[cb + cq * 4 + 1]), 0.f);
      float v2 = fmaxf(fmaf(o2, rg1[cb + cq * 4 + 2] * kBNS, rb1[cb + cq * 4 + 2]), 0.f);
      float v3 = fmaxf(fmaf(o3, rg1[cb + cq * 4 + 3] * kBNS, rb1[cb + cq * 4 + 3]), 0.f);
#pragma unroll
      for (int off = 1; off < 16; off <<= 1) {
        v0 = fmaxf(v0, __shfl_xor(v0, off, 64));
        v1 = fmaxf(v1, __shfl_xor(v1, off, 64));
        v2 = fmaxf(v2, __shfl_xor(v2, off, 64));
        v3 = fmaxf(v3, __shfl_xor(v3, off, 64));
      }
      if (sL == 0) {
        featsL[outoff + cq * 4 + 0] = v0;
        featsL[outoff + cq * 4 + 1] = v1;
        featsL[outoff + cq * 4 + 2] = v2;
        featsL[outoff + cq * 4 + 3] = v3;
      }
    }
  } else {
    // conv SA (identical math to r6 conv_sa_kernel), ri = wv-2
    const int ri = wv - 2;
    const int NS = ri ? 32 : 16;
    const float R2 = ri ? (float)(2.4 * 2.4) : (float)(1.2 * 1.2);
    const int cbase = bb * MVOX;
    int cnt = 0;
    {
#pragma clang fp contract(off)
      for (int ch = 0; ch < MVOX / 64 && cnt < NS; ++ch) {
        const float4 q = cxyz4[cbase + ch * 64 + lane];
        float dx = kxv - q.x, dy = kyv - q.y, dz = kzv - q.z;
        float d2 = dx * dx; d2 = d2 + dy * dy; d2 = d2 + dz * dz;
        unsigned long long m = __ballot(d2 < R2);
        while (m && cnt < NS) {
          int bit = __builtin_ctzll(m);
          if (lane == 0) idxlC[ri][cnt] = ch * 64 + bit;
          ++cnt;
          m &= m - 1;
        }
      }
    }
    const int outoff = 288 + ri * 64;
    if (cnt == 0) {
      featsL[outoff + lane] = 0.f;
    } else {
      __threadfence_block();
      // per-lane weight columns (lane == output channel), register-resident
      const float wA0 = cw0[(ri * 67 + 0) * 64 + lane];
      const float wA1 = cw0[(ri * 67 + 1) * 64 + lane];
      const float wA2 = cw0[(ri * 67 + 2) * 64 + lane];
      float wB[64];
#pragma unroll
      for (int k = 0; k < 64; ++k) wB[k] = cw0[(ri * 67 + 3 + k) * 64 + lane];
      float wC[64];
#pragma unroll
      for (int k = 0; k < 64; ++k) wC[k] = cw1[(ri * 64 + k) * 64 + lane];
      const float s0 = cg0[ri * 64 + lane] * kBNS, bb0 = cb0[ri * 64 + lane];
      const float s1 = cg1[ri * 64 + lane] * kBNS, bb1 = cb1[ri * 64 + lane];

      for (int sm = 0; sm < cnt; ++sm) {
        const int p = cbase + idxlC[ri][sm];
        const float4 q = cxyz4[p];
        const float ox = q.x - kxv, oy = q.y - kyv, oz = q.z - kzv;
        gbuf[ri][lane] = vf[(size_t)p * 64 + lane];
        __threadfence_block();
        float acc = ox * wA0;
        acc = fmaf(oy, wA1, acc);
        acc = fmaf(oz, wA2, acc);
#pragma unroll
        for (int k4 = 0; k4 < 16; ++k4) {
          float4 g4 = *(const float4*)&gbuf[ri][k4 * 4];
          acc = fmaf(g4.x, wB[k4 * 4 + 0], acc);
          acc = fmaf(g4.y, wB[k4 * 4 + 1], acc);
          acc = fmaf(g4.z, wB[k4 * 4 + 2], acc);
          acc = fmaf(g4.w, wB[k4 * 4 + 3], acc);
        }
        hbufC[ri][sm][lane] = fmaxf(fmaf(acc, s0, bb0), 0.f);
        __threadfence_block();
      }
      float mx = -1e30f;
      for (int sm = 0; sm < cnt; ++sm) {
        float acc = 0.f;
#pragma unroll
        for (int k4 = 0; k4 < 16; ++k4) {
          float4 h4 = *(const float4*)&hbufC[ri][sm][k4 * 4];
          acc = fmaf(h4.x, wC[k4 * 4 + 0], acc);
          acc = fmaf(h4.y, wC[k4 * 4 + 1], acc);
          acc = fmaf(h4.z, wC[k4 * 4 + 2], acc);
          acc = fmaf(h4.w, wC[k4 * 4 + 3], acc);
        }
        mx = fmaxf(mx, fmaxf(fmaf(acc, s1, bb1), 0.f));
      }
      featsL[outoff + lane] = mx;
    }
  }
  __syncthreads();

  // ---- Phase C: fusion 416 -> 128 (identical math), c = t < 128 ----
  if (t < 128) {
    const int c = t;
    float acc = 0.f;
#pragma unroll 4
    for (int k = 0; k < 416; k += 4) {
      float4 fv = *(const float4*)(featsL + k);
      acc = fmaf(fv.x, fw[(k + 0) * 128 + c], acc);
      acc = fmaf(fv.y, fw[(k + 1) * 128 + c], acc);
      acc = fmaf(fv.z, fw[(k + 2) * 128 + c], acc);
      acc = fmaf(fv.w, fw[(k + 3) * 128 + c], acc);
    }
    out[(size_t)kidx * 128 + c] = fmaxf(fmaf(acc, fg[c] * kBNS, fb[c]), 0.f);
  }
}

// ---------------------------------------------------------------------------
extern "C" void kernel_launch(void* const* d_in, const int* in_sizes, int n_in,
                              void* d_out, int out_size, void* d_ws, size_t ws_size,
                              hipStream_t stream) {
  (void)in_sizes; (void)n_in; (void)out_size; (void)ws_size;
  const float* pts = (const float*)d_in[0];
  const float* sf  = (const float*)d_in[1];
  const int*   vc  = (const int*)d_in[2];
  const float* vf  = (const float*)d_in[3];
  const float* raw_w0 = (const float*)d_in[4];
  const float* raw_g0 = (const float*)d_in[5];
  const float* raw_b0 = (const float*)d_in[6];
  const float* raw_w1 = (const float*)d_in[7];
  const float* raw_g1 = (const float*)d_in[8];
  const float* raw_b1 = (const float*)d_in[9];
  const float* conv_w0 = (const float*)d_in[10];
  const float* conv_g0 = (const float*)d_in[11];
  const float* conv_b0 = (const float*)d_in[12];
  const float* conv_w1 = (const float*)d_in[13];
  const float* conv_g1 = (const float*)d_in[14];
  const float* conv_b1 = (const float*)d_in[15];
  const float* fus_w = (const float*)d_in[16];
  const float* fus_g = (const float*)d_in[17];
  const float* fus_b = (const float*)d_in[18];
  float* out = (float*)d_out;

  float* W = (float*)d_ws;
  float4* xyz4  = (float4*)W;             // 32768 float4 = 131072 floats
  float4* cxyz4 = (float4*)(W + 131072);  // 16384 float4 = 65536 floats
  float* kx    = W + 196608;              // 4096 each
  float* ky    = W + 200704;
  float* kz    = W + 204800;
  int* sperm   = (int*)(W + 208896);      // 32768 ints

  sort_prep_kernel<<<2, 1024, 0, stream>>>(pts, vc, xyz4, cxyz4, sperm);
  fps_kernel<<<2, 1024, 0, stream>>>(sperm, xyz4, kx, ky, kz);
  post_kernel<<<NKPALL, 256, 0, stream>>>(
      xyz4, cxyz4, vf, sf,
      raw_w0, raw_g0, raw_b0, raw_w1, raw_g1, raw_b1,
      conv_w0, conv_g0, conv_b0, conv_w1, conv_g1, conv_b1,
      fus_w, fus_g, fus_b, kx, ky, kz, out);
}

// Round 12
// 2032.933 us; speedup vs baseline: 1.5423x; 1.2568x over previous
//
#include <hip/hip_runtime.h>

// ---------------------------------------------------------------------------
// VoxelSetAbstraction forward (PV-RCNN style) for MI355X
//   B=2, N_RAW=16384, N_KP=2048, M_VOX=8192, C_VOX=64
//   BEV: (2,256,200,176), stride 8, voxel 0.05, pc_min (0,-40,-3)
//   raw SA: radii (0.4,0.8) ns (16,16), MLP 4->16->16
//   conv SA: radii (1.2,2.4) ns (16,32), MLP 67->64->64
//   fusion: 416 -> 128
//
// r12 = r11 with the two misplaced `#pragma clang fp contract(off)` fixed
// (must open a compound statement). Content otherwise identical:
// r6 split pipeline (proven best: fps 1693us twice) + WINDOWED ball query.
// sort_prep also emits y-sorted coord arrays (xyzs/cxyzs), sorted perms
// (sperm/vsperm) and per-bin offsets (pbin/vbin). SA kernels scan only the
// [ky-r, ky+r] bin window (~5-10 chunks vs 256/128). Selection semantics
// preserved EXACTLY: ref max-pools over grouped samples, so only the SET of
// selected samples matters (pad duplicates a member -> no effect). Set = NS
// smallest-original-index hits: hits<=NS -> hit set; NS<hits<=64 -> NS DPP
// min-extraction rounds; hits>64 -> fallback full original-order scan
// (guaranteed correctness). d^2 predicate op-for-op identical on identical
// float values -> identical hit sets.
// ---------------------------------------------------------------------------

#define NRAW   16384
#define MVOX   8192
#define NKP    2048
#define NKPALL 4096   // B * NKP

__device__ __constant__ float kBNS = (float)0.9999950000374997; // 1/sqrt(1+1e-5)

typedef float f32x2 __attribute__((ext_vector_type(2)));

// ---------------------------------------------------------------------------
// Wave-wide u32 max via DPP (VALU pipe, zero DS). Lane 63 holds the result.
// ---------------------------------------------------------------------------
__device__ __forceinline__ unsigned wave_umax63(unsigned v) {
  unsigned t;
  t = (unsigned)__builtin_amdgcn_update_dpp(0, (int)v, 0xB1,  0xf, 0xf, true); v = v < t ? t : v;
  t = (unsigned)__builtin_amdgcn_update_dpp(0, (int)v, 0x4E,  0xf, 0xf, true); v = v < t ? t : v;
  t = (unsigned)__builtin_amdgcn_update_dpp(0, (int)v, 0x124, 0xf, 0xf, true); v = v < t ? t : v;
  t = (unsigned)__builtin_amdgcn_update_dpp(0, (int)v, 0x128, 0xf, 0xf, true); v = v < t ? t : v;
  t = (unsigned)__builtin_amdgcn_update_dpp(0, (int)v, 0x142, 0xa, 0xf, true); v = v < t ? t : v;
  t = (unsigned)__builtin_amdgcn_update_dpp(0, (int)v, 0x143, 0xc, 0xf, true); v = v < t ? t : v;
  return v;  // valid in lane 63
}

// ---------------------------------------------------------------------------
// K0: per-batch pack + y-histogram sorts (points AND voxel centers).
// Emits: xyz4/cxyz4 (original order), sperm/xyzs/pbin (point y-sort),
// vsperm/cxyzs/vbin (voxel y-sort). Bin formula identical between sort and
// query sides (monotone trunc-affine) -> window superset guaranteed; +-1 bin
// slack added at query time for float-edge safety.
// ---------------------------------------------------------------------------
__global__ __launch_bounds__(1024) void sort_prep_kernel(
    const float* __restrict__ pts, const int* __restrict__ vc,
    float4* __restrict__ xyz4, float4* __restrict__ cxyz4,
    int* __restrict__ sperm, float4* __restrict__ xyzs,
    int* __restrict__ pbin,
    int* __restrict__ vsperm, float4* __restrict__ cxyzs,
    int* __restrict__ vbin) {
#pragma clang fp contract(off)
  const int b = blockIdx.x, t = threadIdx.x;
  // pack this batch's points + voxel centers (original order)
  for (int i = t; i < NRAW; i += 1024) {
    const float* p = pts + (size_t)(b * NRAW + i) * 5;
    xyz4[b * NRAW + i] = make_float4(p[1], p[2], p[3], p[4]);
  }
  for (int i = t; i < MVOX; i += 1024) {
    const int* v = vc + (size_t)(b * MVOX + i) * 4;
    cxyz4[b * MVOX + i] = make_float4(((float)v[3] + 0.5f) * 0.2f + 0.0f,
                                      ((float)v[2] + 0.5f) * 0.2f + -40.0f,
                                      ((float)v[1] + 0.5f) * 0.4f + -3.0f, 0.f);
  }

  __shared__ unsigned hist[256], cur[256];

  // ---------------- points: y histogram sort ----------------
  if (t < 256) hist[t] = 0u;
  __syncthreads();
  int bins[16];
#pragma unroll
  for (int k = 0; k < 16; ++k) {
    const int i = k * 1024 + t;
    const float y = pts[(size_t)(b * NRAW + i) * 5 + 2];
    int bin = (int)((y + 40.0f) * 3.2f);
    bin = bin < 0 ? 0 : (bin > 255 ? 255 : bin);
    bins[k] = bin;
    atomicAdd(&hist[bin], 1u);
  }
  __syncthreads();
  if (t == 0) {
    unsigned acc = 0;
    for (int i = 0; i < 256; ++i) { cur[i] = acc; acc += hist[i]; }
  }
  __syncthreads();
  if (t < 256) pbin[b * 257 + t] = (int)cur[t];
  if (t == 0)  pbin[b * 257 + 256] = NRAW;
  __syncthreads();
#pragma unroll
  for (int k = 0; k < 16; ++k) {
    const int i = k * 1024 + t;
    const float* p = pts + (size_t)(b * NRAW + i) * 5;
    const unsigned pos = atomicAdd(&cur[bins[k]], 1u);
    sperm[b * NRAW + pos] = i;
    xyzs[b * NRAW + pos] = make_float4(p[1], p[2], p[3], p[4]);
  }
  __syncthreads();

  // ---------------- voxels: y histogram sort ----------------
  if (t < 256) hist[t] = 0u;
  __syncthreads();
  int vbins[8];
#pragma unroll
  for (int k = 0; k < 8; ++k) {
    const int i = k * 1024 + t;
    const int* v = vc + (size_t)(b * MVOX + i) * 4;
    const float cy = ((float)v[2] + 0.5f) * 0.2f + -40.0f;
    int bin = (int)((cy + 40.0f) * 3.2f);
    bin = bin < 0 ? 0 : (bin > 255 ? 255 : bin);
    vbins[k] = bin;
    atomicAdd(&hist[bin], 1u);
  }
  __syncthreads();
  if (t == 0) {
    unsigned acc = 0;
    for (int i = 0; i < 256; ++i) { cur[i] = acc; acc += hist[i]; }
  }
  __syncthreads();
  if (t < 256) vbin[b * 257 + t] = (int)cur[t];
  if (t == 0)  vbin[b * 257 + 256] = MVOX;
  __syncthreads();
#pragma unroll
  for (int k = 0; k < 8; ++k) {
    const int i = k * 1024 + t;
    const int* v = vc + (size_t)(b * MVOX + i) * 4;
    const unsigned pos = atomicAdd(&cur[vbins[k]], 1u);
    vsperm[b * MVOX + pos] = i;
    cxyzs[b * MVOX + pos] = make_float4(((float)v[3] + 0.5f) * 0.2f + 0.0f,
                                        ((float)v[2] + 0.5f) * 0.2f + -40.0f,
                                        ((float)v[1] + 0.5f) * 0.4f + -3.0f, 0.f);
  }
}

// Fused 64-bit DPP max-reduce stage (proven r6). After the 6-stage ladder the
// wave max of (hi:lo) lives in lane 63.
#define U64_STAGE(CTRL, RMASK)                                                 \
  {                                                                            \
    const unsigned tlo = (unsigned)__builtin_amdgcn_update_dpp(                \
        0, (int)lo, CTRL, RMASK, 0xf, true);                                   \
    const unsigned thi = (unsigned)__builtin_amdgcn_update_dpp(                \
        0, (int)hi, CTRL, RMASK, 0xf, true);                                   \
    const unsigned long long tv = ((unsigned long long)thi << 32) | tlo;       \
    const unsigned long long cv = ((unsigned long long)hi << 32) | lo;         \
    if (tv > cv) { hi = thi; lo = tlo; }                                       \
  }

// ---------------------------------------------------------------------------
// K1: farthest point sampling -- byte-identical to the proven r6/r10 version
// (1693us isolated, reproduced twice).
// ---------------------------------------------------------------------------
__global__ __launch_bounds__(1024, 4) void fps_kernel(
    const int* __restrict__ sperm, const float4* __restrict__ xyz4,
    float* __restrict__ kx, float* __restrict__ ky, float* __restrict__ kz) {
#pragma clang fp contract(off)
  const int b = blockIdx.x;
  const int t = threadIdx.x;
  const int w = t >> 6, lane = t & 63;
  const int wb = w * 1024;
  const int base = b * NRAW;

  __shared__ unsigned long long slot[3];

  int pj[16];
  f32x2 px2[8], py2[8], pz2[8], dd2[8];
#pragma unroll
  for (int j = 0; j < 16; ++j)
    pj[j] = sperm[base + wb + j * 64 + lane];
#pragma unroll
  for (int j = 0; j < 16; ++j) {
    const float4 q = xyz4[base + pj[j]];   // gather; warms local L2 with batch
    px2[j >> 1][j & 1] = q.x;
    py2[j >> 1][j & 1] = q.y;
    pz2[j >> 1][j & 1] = q.z;
    dd2[j >> 1][j & 1] = 1e10f;
  }
  if (t < 3) slot[t] = 0ULL;

  float bnx = px2[0].x, bxx = px2[0].x, bny = py2[0].x, bxy = py2[0].x,
        bnz = pz2[0].x, bxz = pz2[0].x;
#pragma unroll
  for (int j = 1; j < 16; ++j) {
    bnx = fminf(bnx, px2[j >> 1][j & 1]); bxx = fmaxf(bxx, px2[j >> 1][j & 1]);
    bny = fminf(bny, py2[j >> 1][j & 1]); bxy = fmaxf(bxy, py2[j >> 1][j & 1]);
    bnz = fminf(bnz, pz2[j >> 1][j & 1]); bxz = fmaxf(bxz, pz2[j >> 1][j & 1]);
  }
#pragma unroll
  for (int off = 1; off < 64; off <<= 1) {
    bnx = fminf(bnx, __shfl_xor(bnx, off, 64));
    bxx = fmaxf(bxx, __shfl_xor(bxx, off, 64));
    bny = fminf(bny, __shfl_xor(bny, off, 64));
    bxy = fmaxf(bxy, __shfl_xor(bxy, off, 64));
    bnz = fminf(bnz, __shfl_xor(bnz, off, 64));
    bxz = fmaxf(bxz, __shfl_xor(bxz, off, 64));
  }

  const float4 p0 = xyz4[base];           // first keypoint = original idx 0
  float lx = p0.x, ly = p0.y, lz = p0.z;
  if (t == 0) { kx[b * NKP] = lx; ky[b * NKP] = ly; kz[b * NKP] = lz; }

  unsigned long long cpk = 0ULL;          // cached (val<<32 | ~minidx), lane63
  float bvc = __builtin_inff();           // cached wave max dd (inf: no skip)
  __syncthreads();

  for (int s = 1; s < NKP; ++s) {
    float dxm = fmaxf(fmaxf(bnx - lx, lx - bxx), 0.f);
    float dym = fmaxf(fmaxf(bny - ly, ly - bxy), 0.f);
    float dzm = fmaxf(fmaxf(bnz - lz, lz - bxz), 0.f);
    const float LB2 = dxm * dxm + dym * dym + dzm * dzm;
    if (!(LB2 * 0.9999f > bvc)) {         // active
      const f32x2 lx2 = {lx, lx}, ly2 = {ly, ly}, lz2 = {lz, lz};
#pragma unroll
      for (int j8 = 0; j8 < 8; ++j8) {    // packed: 2 points per op
        f32x2 dx = px2[j8] - lx2;
        f32x2 dy = py2[j8] - ly2;
        f32x2 dz = pz2[j8] - lz2;
        f32x2 d2 = dx * dx;
        d2 = d2 + dy * dy;
        d2 = d2 + dz * dz;
        dd2[j8] = __builtin_elementwise_min(dd2[j8], d2);
      }
      f32x2 t0 = __builtin_elementwise_max(dd2[0], dd2[1]);
      f32x2 t1 = __builtin_elementwise_max(dd2[2], dd2[3]);
      f32x2 t2 = __builtin_elementwise_max(dd2[4], dd2[5]);
      f32x2 t3 = __builtin_elementwise_max(dd2[6], dd2[7]);
      t0 = __builtin_elementwise_max(t0, t1);
      t2 = __builtin_elementwise_max(t2, t3);
      t0 = __builtin_elementwise_max(t0, t2);
      const float bv = fmaxf(t0.x, t0.y);
      const unsigned vb = __float_as_uint(bv);
      unsigned mo = 0xFFFFFFFFu;
#pragma unroll
      for (int j = 0; j < 16; ++j)
        if (__float_as_uint(dd2[j >> 1][j & 1]) == vb) {
          const unsigned o = (unsigned)pj[j];
          mo = o < mo ? o : mo;
        }
      unsigned hi = vb, lo = ~mo;
      U64_STAGE(0xB1,  0xf)
      U64_STAGE(0x4E,  0xf)
      U64_STAGE(0x124, 0xf)
      U64_STAGE(0x128, 0xf)
      U64_STAGE(0x142, 0xa)
      U64_STAGE(0x143, 0xc)
      bvc = __uint_as_float(
          (unsigned)__builtin_amdgcn_readlane((int)hi, 63));
      cpk = ((unsigned long long)hi << 32) | (unsigned long long)lo;
    }
    if (lane == 63) atomicMax(&slot[s % 3], cpk);
    __syncthreads();

    const unsigned long long g = slot[s % 3];
    const int wi = __builtin_amdgcn_readfirstlane((int)~(unsigned)g);
    if (t == 0) slot[(s + 2) % 3] = 0ULL;     // next used at iter s+2
    const float4 cw = xyz4[base + wi];        // uniform s_load, L2-warm
    lx = cw.x; ly = cw.y; lz = cw.z;
    if (t == 0) { kx[b * NKP + s] = lx; ky[b * NKP + s] = ly; kz[b * NKP + s] = lz; }
  }
}

// ---------------------------------------------------------------------------
// K2: BEV bilinear (r6 verbatim). one block per keypoint, 256 ch.
// ---------------------------------------------------------------------------
__global__ __launch_bounds__(256) void bev_kernel(
    const float* __restrict__ sf, const float* __restrict__ kx,
    const float* __restrict__ ky, float* __restrict__ feats) {
#pragma clang fp contract(off)
  const int kidx = blockIdx.x;
  const int c = threadIdx.x;
  const int b = kidx >> 11;
  const float x = (kx[kidx] - 0.0f) / 0.05f / 8.0f;
  const float y = (ky[kidx] - (-40.0f)) / 0.05f / 8.0f;
  const float xf = floorf(x), yf = floorf(y);
  int x0 = (int)xf;     x0 = x0 < 0 ? 0 : (x0 > 175 ? 175 : x0);
  int x1 = (int)xf + 1; x1 = x1 < 0 ? 0 : (x1 > 175 ? 175 : x1);
  int y0 = (int)yf;     y0 = y0 < 0 ? 0 : (y0 > 199 ? 199 : y0);
  int y1 = (int)yf + 1; y1 = y1 < 0 ? 0 : (y1 > 199 ? 199 : y1);
  const float x0f = (float)x0, x1f = (float)x1, y0f = (float)y0, y1f = (float)y1;
  const float wa = (x - x0f) * (y1f - y);
  const float wb = (x1f - x) * (y1f - y);
  const float wc = (x1f - x) * (y - y0f);
  const float wd = (x - x0f) * (y - y0f);
  const float* base = sf + ((size_t)b * 256 + c) * (200 * 176);
  const float fa = base[y1 * 176 + x0];
  const float fb = base[y1 * 176 + x1];
  const float fc = base[y0 * 176 + x1];
  const float fd = base[y0 * 176 + x0];
  float r = fd * wb; r = r + fc * wa; r = r + fa * wc; r = r + fb * wd;
  feats[(size_t)kidx * 416 + c] = r;
}

// ---------------------------------------------------------------------------
// K3: raw SA with windowed ball query. one wave per (keypoint, radius).
// Hit set == ref's selected set (max-pool invariance; see header comment).
// ---------------------------------------------------------------------------
__global__ __launch_bounds__(256) void raw_sa_kernel(
    const float4* __restrict__ xyz4, const float4* __restrict__ xyzs,
    const int* __restrict__ sperm, const int* __restrict__ pbin,
    const float* __restrict__ kx, const float* __restrict__ ky,
    const float* __restrict__ kz,
    const float* __restrict__ w0, const float* __restrict__ g0,
    const float* __restrict__ b0, const float* __restrict__ w1,
    const float* __restrict__ g1, const float* __restrict__ b1,
    float* __restrict__ feats) {
  const int wv = threadIdx.x >> 6;
  const int lane = threadIdx.x & 63;
  const int gw = blockIdx.x * 4 + wv;       // 0..8191
  const int ri = gw >> 12;                  // radius index 0/1
  const int kidx = gw & 4095;
  const int b = kidx >> 11;
  const float R  = ri ? 0.8f : 0.4f;
  const float R2 = ri ? (float)(0.8 * 0.8) : (float)(0.4 * 0.4);

  __shared__ int   hlist[4][64];
  __shared__ float hbuf[4][16][17];

  const float kxv = kx[kidx], kyv = ky[kidx], kzv = kz[kidx];
  const int base = b * NRAW;
  int cnt = 0, hits = 0;
  {
#pragma clang fp contract(off)
    int b0i = (int)((kyv - R + 40.0f) * 3.2f) - 1;
    b0i = b0i < 0 ? 0 : (b0i > 255 ? 255 : b0i);
    int b1i = (int)((kyv + R + 40.0f) * 3.2f) + 1;
    b1i = b1i < 0 ? 0 : (b1i > 255 ? 255 : b1i);
    const int s0 = pbin[b * 257 + b0i];
    const int s1 = pbin[b * 257 + b1i + 1];
    if (s1 > s0) {
      const int c0 = s0 >> 6, c1 = (s1 - 1) >> 6;
      for (int ch = c0; ch <= c1; ++ch) {
        const int pos = ch * 64 + lane;
        const float4 q = xyzs[base + pos];
        const int og = sperm[base + pos];
        float dx = kxv - q.x, dy = kyv - q.y, dz = kzv - q.z;
        float d2 = dx * dx; d2 = d2 + dy * dy; d2 = d2 + dz * dz;
        const bool hit = (pos >= s0) && (pos < s1) && (d2 < R2);
        unsigned long long m = __ballot(hit);
        hits += __popcll(m);
        while (m && cnt < 64) {
          const int bit = __builtin_ctzll(m);
          const int o = __shfl(og, bit, 64);
          if (lane == 0) hlist[wv][cnt] = o;
          ++cnt;
          m &= m - 1;
        }
      }
    }
  }
  if (hits > 64) {
    // fallback: classic full original-order scan (guaranteed-correct path)
    cnt = 0;
    {
#pragma clang fp contract(off)
      for (int ch = 0; ch < NRAW / 64 && cnt < 16; ++ch) {
        const float4 q = xyz4[base + ch * 64 + lane];
        float dx = kxv - q.x, dy = kyv - q.y, dz = kzv - q.z;
        float d2 = dx * dx; d2 = d2 + dy * dy; d2 = d2 + dz * dz;
        unsigned long long m = __ballot(d2 < R2);
        while (m && cnt < 16) {
          const int bit = __builtin_ctzll(m);
          if (lane == 0) hlist[wv][cnt] = ch * 64 + bit;
          ++cnt;
          m &= m - 1;
        }
      }
    }
  } else if (hits > 16) {
    // select the 16 smallest original indices (exact ref set)
    __threadfence_block();
    unsigned val = (lane < cnt) ? (unsigned)hlist[wv][lane] : 0xFFFFFFFFu;
    for (int k = 0; k < 16; ++k) {
      const unsigned mn =
          ~(unsigned)__builtin_amdgcn_readlane((int)wave_umax63(~val), 63);
      if (lane == 0) hlist[wv][k] = (int)mn;
      if (val == mn) val = 0xFFFFFFFFu;
    }
    cnt = 16;
  } else {
    cnt = hits;
  }
  const int outoff = kidx * 416 + 256 + ri * 16;
  if (cnt == 0) {
    if (lane < 16) feats[outoff + lane] = 0.f;
    return;
  }
  __threadfence_block();

  const int s = lane & 15, cq = lane >> 4;
  const int ss = (s < cnt) ? s : 0;          // duplicate member (max-pool inv)
  const float4 q = xyz4[base + hlist[wv][ss]];
  const float gx = q.x - kxv, gy = q.y - kyv, gz = q.z - kzv, gi = q.w;
  const int wb0 = ri * 64, cb = ri * 16;
#pragma unroll
  for (int j = 0; j < 4; ++j) {
    int c = cq * 4 + j;
    float a = gx * w0[wb0 + c];
    a = fmaf(gy, w0[wb0 + 16 + c], a);
    a = fmaf(gz, w0[wb0 + 32 + c], a);
    a = fmaf(gi, w0[wb0 + 48 + c], a);
    a = fmaf(a, g0[cb + c] * kBNS, b0[cb + c]);
    hbuf[wv][s][c] = fmaxf(a, 0.f);
  }
  __threadfence_block();
  float o0 = 0.f, o1 = 0.f, o2 = 0.f, o3 = 0.f;
  const int wb1 = ri * 256;
#pragma unroll
  for (int k = 0; k < 16; ++k) {
    float hk = hbuf[wv][s][k];
    o0 = fmaf(hk, w1[wb1 + k * 16 + cq * 4 + 0], o0);
    o1 = fmaf(hk, w1[wb1 + k * 16 + cq * 4 + 1], o1);
    o2 = fmaf(hk, w1[wb1 + k * 16 + cq * 4 + 2], o2);
    o3 = fmaf(hk, w1[wb1 + k * 16 + cq * 4 + 3], o3);
  }
  float v0 = fmaxf(fmaf(o0, g1[cb + cq * 4 + 0] * kBNS, b1[cb + cq * 4 + 0]), 0.f);
  float v1 = fmaxf(fmaf(o1, g1[cb + cq * 4 + 1] * kBNS, b1[cb + cq * 4 + 1]), 0.f);
  float v2 = fmaxf(fmaf(o2, g1[cb + cq * 4 + 2] * kBNS, b1[cb + cq * 4 + 2]), 0.f);
  float v3 = fmaxf(fmaf(o3, g1[cb + cq * 4 + 3] * kBNS, b1[cb + cq * 4 + 3]), 0.f);
#pragma unroll
  for (int off = 1; off < 16; off <<= 1) {
    v0 = fmaxf(v0, __shfl_xor(v0, off, 64));
    v1 = fmaxf(v1, __shfl_xor(v1, off, 64));
    v2 = fmaxf(v2, __shfl_xor(v2, off, 64));
    v3 = fmaxf(v3, __shfl_xor(v3, off, 64));
  }
  if (s == 0) {
    feats[outoff + cq * 4 + 0] = v0;
    feats[outoff + cq * 4 + 1] = v1;
    feats[outoff + cq * 4 + 2] = v2;
    feats[outoff + cq * 4 + 3] = v3;
  }
}

// ---------------------------------------------------------------------------
// K4: conv SA with windowed ball query. one wave per (keypoint, radius).
// ---------------------------------------------------------------------------
__global__ __launch_bounds__(256) void conv_sa_kernel(
    const float4* __restrict__ cxyz4, const float4* __restrict__ cxyzs,
    const int* __restrict__ vsperm, const int* __restrict__ vbin,
    const float* __restrict__ vf,
    const float* __restrict__ kx, const float* __restrict__ ky,
    const float* __restrict__ kz,
    const float* __restrict__ w0, const float* __restrict__ g0,
    const float* __restrict__ b0, const float* __restrict__ w1,
    const float* __restrict__ g1, const float* __restrict__ b1,
    float* __restrict__ feats) {
  const int wv = threadIdx.x >> 6;
  const int lane = threadIdx.x & 63;
  const int gw = blockIdx.x * 4 + wv;
  const int ri = gw >> 12;
  const int kidx = gw & 4095;
  const int b = kidx >> 11;
  const int NS = ri ? 32 : 16;
  const float R  = ri ? 2.4f : 1.2f;
  const float R2 = ri ? (float)(2.4 * 2.4) : (float)(1.2 * 1.2);

  __shared__ int   hlist[4][64];
  __shared__ float gbuf[4][64];
  __shared__ float hbufC[4][32][64];

  const float kxv = kx[kidx], kyv = ky[kidx], kzv = kz[kidx];
  const int base = b * MVOX;
  int cnt = 0, hits = 0;
  {
#pragma clang fp contract(off)
    int b0i = (int)((kyv - R + 40.0f) * 3.2f) - 1;
    b0i = b0i < 0 ? 0 : (b0i > 255 ? 255 : b0i);
    int b1i = (int)((kyv + R + 40.0f) * 3.2f) + 1;
    b1i = b1i < 0 ? 0 : (b1i > 255 ? 255 : b1i);
    const int s0 = vbin[b * 257 + b0i];
    const int s1 = vbin[b * 257 + b1i + 1];
    if (s1 > s0) {
      const int c0 = s0 >> 6, c1 = (s1 - 1) >> 6;
      for (int ch = c0; ch <= c1; ++ch) {
        const int pos = ch * 64 + lane;
        const float4 q = cxyzs[base + pos];
        const int og = vsperm[base + pos];
        float dx = kxv - q.x, dy = kyv - q.y, dz = kzv - q.z;
        float d2 = dx * dx; d2 = d2 + dy * dy; d2 = d2 + dz * dz;
        const bool hit = (pos >= s0) && (pos < s1) && (d2 < R2);
        unsigned long long m = __ballot(hit);
        hits += __popcll(m);
        while (m && cnt < 64) {
          const int bit = __builtin_ctzll(m);
          const int o = __shfl(og, bit, 64);
          if (lane == 0) hlist[wv][cnt] = o;
          ++cnt;
          m &= m - 1;
        }
      }
    }
  }
  if (hits > 64) {
    // fallback: classic full original-order scan
    cnt = 0;
    {
#pragma clang fp contract(off)
      for (int ch = 0; ch < MVOX / 64 && cnt < NS; ++ch) {
        const float4 q = cxyz4[base + ch * 64 + lane];
        float dx = kxv - q.x, dy = kyv - q.y, dz = kzv - q.z;
        float d2 = dx * dx; d2 = d2 + dy * dy; d2 = d2 + dz * dz;
        unsigned long long m = __ballot(d2 < R2);
        while (m && cnt < NS) {
          const int bit = __builtin_ctzll(m);
          if (lane == 0) hlist[wv][cnt] = ch * 64 + bit;
          ++cnt;
          m &= m - 1;
        }
      }
    }
  } else if (hits > NS) {
    // select the NS smallest original indices (exact ref set)
    __threadfence_block();
    unsigned val = (lane < cnt) ? (unsigned)hlist[wv][lane] : 0xFFFFFFFFu;
    for (int k = 0; k < NS; ++k) {
      const unsigned mn =
          ~(unsigned)__builtin_amdgcn_readlane((int)wave_umax63(~val), 63);
      if (lane == 0) hlist[wv][k] = (int)mn;
      if (val == mn) val = 0xFFFFFFFFu;
    }
    cnt = NS;
  } else {
    cnt = hits;
  }
  const int outoff = kidx * 416 + 288 + ri * 64;
  if (cnt == 0) {
    feats[outoff + lane] = 0.f;
    return;
  }
  __threadfence_block();

  // per-lane weight columns (lane == output channel)
  const float wA0 = w0[(ri * 67 + 0) * 64 + lane];
  const float wA1 = w0[(ri * 67 + 1) * 64 + lane];
  const float wA2 = w0[(ri * 67 + 2) * 64 + lane];
  float wB[64];
#pragma unroll
  for (int k = 0; k < 64; ++k) wB[k] = w0[(ri * 67 + 3 + k) * 64 + lane];
  float wC[64];
#pragma unroll
  for (int k = 0; k < 64; ++k) wC[k] = w1[(ri * 64 + k) * 64 + lane];
  const float s0 = g0[ri * 64 + lane] * kBNS, bb0 = b0[ri * 64 + lane];
  const float s1 = g1[ri * 64 + lane] * kBNS, bb1 = b1[ri * 64 + lane];

  for (int sm = 0; sm < cnt; ++sm) {
    const int p = base + hlist[wv][sm];
    const float4 q = cxyz4[p];
    const float ox = q.x - kxv, oy = q.y - kyv, oz = q.z - kzv;
    gbuf[wv][lane] = vf[(size_t)p * 64 + lane];
    __threadfence_block();
    float acc = ox * wA0;
    acc = fmaf(oy, wA1, acc);
    acc = fmaf(oz, wA2, acc);
#pragma unroll
    for (int k4 = 0; k4 < 16; ++k4) {
      float4 g4 = *(const float4*)&gbuf[wv][k4 * 4];
      acc = fmaf(g4.x, wB[k4 * 4 + 0], acc);
      acc = fmaf(g4.y, wB[k4 * 4 + 1], acc);
      acc = fmaf(g4.z, wB[k4 * 4 + 2], acc);
      acc = fmaf(g4.w, wB[k4 * 4 + 3], acc);
    }
    hbufC[wv][sm][lane] = fmaxf(fmaf(acc, s0, bb0), 0.f);
    __threadfence_block();
  }
  float mx = -1e30f;
  for (int sm = 0; sm < cnt; ++sm) {
    float acc = 0.f;
#pragma unroll
    for (int k4 = 0; k4 < 16; ++k4) {
      float4 h4 = *(const float4*)&hbufC[wv][sm][k4 * 4];
      acc = fmaf(h4.x, wC[k4 * 4 + 0], acc);
      acc = fmaf(h4.y, wC[k4 * 4 + 1], acc);
      acc = fmaf(h4.z, wC[k4 * 4 + 2], acc);
      acc = fmaf(h4.w, wC[k4 * 4 + 3], acc);
    }
    mx = fmaxf(mx, fmaxf(fmaf(acc, s1, bb1), 0.f));
  }
  feats[outoff + lane] = mx;
}

// ---------------------------------------------------------------------------
// K5: fusion 416 -> 128 + BN + ReLU (r6 verbatim).
// ---------------------------------------------------------------------------
__global__ __launch_bounds__(256) void fusion_kernel(
    const float* __restrict__ feats, const float* __restrict__ fw,
    const float* __restrict__ fg, const float* __restrict__ fb,
    float* __restrict__ out) {
  const int gid = blockIdx.x * 256 + threadIdx.x;
  const int kidx = gid >> 7, c = gid & 127;
  const float* f = feats + (size_t)kidx * 416;
  float acc = 0.f;
#pragma unroll 4
  for (int k = 0; k < 416; k += 4) {
    float4 fv = *(const float4*)(f + k);
    acc = fmaf(fv.x, fw[(k + 0) * 128 + c], acc);
    acc = fmaf(fv.y, fw[(k + 1) * 128 + c], acc);
    acc = fmaf(fv.z, fw[(k + 2) * 128 + c], acc);
    acc = fmaf(fv.w, fw[(k + 3) * 128 + c], acc);
  }
  out[gid] = fmaxf(fmaf(acc, fg[c] * kBNS, fb[c]), 0.f);
}

// ---------------------------------------------------------------------------
extern "C" void kernel_launch(void* const* d_in, const int* in_sizes, int n_in,
                              void* d_out, int out_size, void* d_ws, size_t ws_size,
                              hipStream_t stream) {
  (void)in_sizes; (void)n_in; (void)out_size; (void)ws_size;
  const float* pts = (const float*)d_in[0];
  const float* sf  = (const float*)d_in[1];
  const int*   vc  = (const int*)d_in[2];
  const float* vf  = (const float*)d_in[3];
  const float* raw_w0 = (const float*)d_in[4];
  const float* raw_g0 = (const float*)d_in[5];
  const float* raw_b0 = (const float*)d_in[6];
  const float* raw_w1 = (const float*)d_in[7];
  const float* raw_g1 = (const float*)d_in[8];
  const float* raw_b1 = (const float*)d_in[9];
  const float* conv_w0 = (const float*)d_in[10];
  const float* conv_g0 = (const float*)d_in[11];
  const float* conv_b0 = (const float*)d_in[12];
  const float* conv_w1 = (const float*)d_in[13];
  const float* conv_g1 = (const float*)d_in[14];
  const float* conv_b1 = (const float*)d_in[15];
  const float* fus_w = (const float*)d_in[16];
  const float* fus_g = (const float*)d_in[17];
  const float* fus_b = (const float*)d_in[18];
  float* out = (float*)d_out;

  float* W = (float*)d_ws;
  float4* xyz4  = (float4*)W;               // 32768 float4
  float4* cxyz4 = (float4*)(W + 131072);    // 16384 float4
  float* kx     = W + 196608;               // 4096 each
  float* ky     = W + 200704;
  float* kz     = W + 204800;
  float* feats  = W + 208896;               // 4096*416 = 1703936 floats
  int*   sperm  = (int*)(W + 1912832);      // 32768 ints
  float4* xyzs  = (float4*)(W + 1945600);   // 32768 float4 (16B-aligned off)
  int*   vsperm = (int*)(W + 2076672);      // 16384 ints
  float4* cxyzs = (float4*)(W + 2093056);   // 16384 float4 (16B-aligned off)
  int*   pbin   = (int*)(W + 2158592);      // 2*257 ints
  int*   vbin   = (int*)(W + 2159106);      // 2*257 ints

  sort_prep_kernel<<<2, 1024, 0, stream>>>(pts, vc, xyz4, cxyz4,
                                           sperm, xyzs, pbin,
                                           vsperm, cxyzs, vbin);
  fps_kernel<<<2, 1024, 0, stream>>>(sperm, xyz4, kx, ky, kz);
  bev_kernel<<<NKPALL, 256, 0, stream>>>(sf, kx, ky, feats);
  raw_sa_kernel<<<2048, 256, 0, stream>>>(xyz4, xyzs, sperm, pbin,
                                          kx, ky, kz,
                                          raw_w0, raw_g0, raw_b0, raw_w1, raw_g1, raw_b1,
                                          feats);
  conv_sa_kernel<<<2048, 256, 0, stream>>>(cxyz4, cxyzs, vsperm, vbin, vf,
                                           kx, ky, kz,
                                           conv_w0, conv_g0, conv_b0, conv_w1, conv_g1, conv_b1,
                                           feats);
  fusion_kernel<<<2048, 256, 0, stream>>>(feats, fus_w, fus_g, fus_b, out);
}